// Round 3
// baseline (2718.340 us; speedup 1.0000x reference)
//
#include <hip/hip_runtime.h>

typedef unsigned short u16;
typedef unsigned int u32;
typedef __attribute__((ext_vector_type(8))) short bf16x8_t;
typedef __attribute__((ext_vector_type(4))) float f32x4_t;

// problem constants
#define kN 65536
#define kE 262144
#define kG 2048
#define kH 300
#define kH2 600
#define kL 5
#define kF 32
#define kDG 1523
// padded dims
#define KP_H 320
#define KP_H2 608
#define KP_DG 1536
#define NP_H2 640
#define NP_H 320
// M-chunking for node MLP
#define C_CHUNK 8
#define C_ROWS (kN / C_CHUNK)   // 8192

__device__ __forceinline__ float bf2f(u16 x) {
    union { u32 u; float f; } v; v.u = ((u32)x) << 16; return v.f;
}
__device__ __forceinline__ u16 f2bf(float f) {
    union { float f; u32 u; } v; v.f = f;
    u32 u = v.u;
    u32 r = (u + 0x7fffu + ((u >> 16) & 1u)) >> 16;  // RNE
    return (u16)r;
}

// ---------------- weight transpose: W[b][k][n] (f32) -> Wt[b][n][k] (bf16), zero-padded ----------------
__global__ void transpose_k(const float* __restrict__ W, u16* __restrict__ Wt,
                            int K, int NN, int NP, int KP, long total) {
    long idx = (long)blockIdx.x * 256 + threadIdx.x;
    if (idx >= total) return;
    int per = NP * KP;
    int b = (int)(idx / per);
    int r = (int)(idx % per);
    int n = r / KP;
    int k = r % KP;
    u16 v = 0;
    if (n < NN && k < K) v = f2bf(W[(long)b * K * NN + (long)k * NN + n]);
    Wt[idx] = v;
}

// ---------------- graph histogram + scan (G=2048) ----------------
__global__ void hist_g_k(const int* __restrict__ batch, int* __restrict__ counts) {
    int n = blockIdx.x * 256 + threadIdx.x;
    if (n < kN) atomicAdd(&counts[batch[n]], 1);
}

__global__ void scan_g_k(const int* __restrict__ counts, int* __restrict__ starts) {
    __shared__ int s[1024];
    int t = threadIdx.x;
    int c0 = counts[2 * t], c1 = counts[2 * t + 1];
    s[t] = c0 + c1;
    __syncthreads();
    for (int off = 1; off < 1024; off <<= 1) {
        int v = (t >= off) ? s[t - off] : 0;
        __syncthreads();
        s[t] += v;
        __syncthreads();
    }
    int excl = (t > 0) ? s[t - 1] : 0;
    starts[2 * t] = excl;
    starts[2 * t + 1] = excl + c0;
}

// ---------------- node CSR build (dst-sorted edges) ----------------
__global__ void hist_n_k(const int* __restrict__ ei, int* __restrict__ cnt) {
    int e = blockIdx.x * 256 + threadIdx.x;
    if (e < kE) atomicAdd(&cnt[ei[kE + e]], 1);  // dst
}

__global__ void scan_n_k(const int* __restrict__ cnt, int* __restrict__ start) {
    __shared__ int s[1024];
    __shared__ int carry;
    int t = threadIdx.x;
    if (t == 0) carry = 0;
    __syncthreads();
    for (int tile = 0; tile < kN / 1024; tile++) {
        int v = cnt[tile * 1024 + t];
        s[t] = v;
        __syncthreads();
        for (int off = 1; off < 1024; off <<= 1) {
            int u = (t >= off) ? s[t - off] : 0;
            __syncthreads();
            s[t] += u;
            __syncthreads();
        }
        start[tile * 1024 + t] = carry + s[t] - v;  // exclusive
        __syncthreads();
        if (t == 1023) carry += s[1023];
        __syncthreads();
    }
    if (t == 0) start[kN] = carry;
}

__global__ void fill_n_k(const int* __restrict__ ei, const int* __restrict__ start,
                         int* __restrict__ fill, int* __restrict__ perm) {
    int e = blockIdx.x * 256 + threadIdx.x;
    if (e >= kE) return;
    int s = ei[e], d = ei[kE + e];
    int pos = start[d] + atomicAdd(&fill[d], 1);
    perm[pos] = s;
}

// ---------------- node embedding: h = x @ W_emb + b_emb ----------------
__global__ void embed_k(const float* __restrict__ x, const float* __restrict__ W,
                        const float* __restrict__ b, float* __restrict__ h) {
    int n = blockIdx.x, j = threadIdx.x;
    if (j >= kH) return;
    float acc = b[j];
    #pragma unroll
    for (int d = 0; d < 9; d++) acc += x[n * 9 + d] * W[d * kH + j];
    h[(long)n * kH + j] = acc;
}

__global__ void vninit_k(const float* __restrict__ vn0, float* __restrict__ vn) {
    int g = blockIdx.x, c = threadIdx.x;
    if (c < kH) vn[g * kH + c] = vn0[c];
}

// ---------------- fused gather + combine:
//   agg[n] = sum_{e in CSR(n)} (h[src_e] + vn[batch[src_e]])
//   hv_in[n] = bf16((1+eps)*(h[n]+vn[batch[n]]) + agg[n]); zero K-pad; zero stats
__global__ void gather_combine_k(const float* __restrict__ h, const float* __restrict__ vn,
                                 const int* __restrict__ batch, const int* __restrict__ start_n,
                                 const int* __restrict__ perm, const float* __restrict__ eps,
                                 int l, u16* __restrict__ hv_in, float* __restrict__ stats) {
    __shared__ int s_src[64];
    __shared__ int s_g[64];
    int n = blockIdx.x, c = threadIdx.x;  // block = 320
    int st = start_n[n], en = start_n[n + 1];
    float acc = 0.f;
    for (int base = st; base < en; base += 64) {
        int m = min(64, en - base);
        __syncthreads();
        if (c < m) { int s = perm[base + c]; s_src[c] = s; s_g[c] = batch[s]; }
        __syncthreads();
        if (c < kH) {
            for (int e = 0; e < m; e++)
                acc += h[(long)s_src[e] * kH + c] + vn[s_g[e] * kH + c];
        }
    }
    if (c < kH) {
        int g = batch[n];
        float ep = 1.f + eps[l];
        float v = ep * (h[(long)n * kH + c] + vn[g * kH + c]) + acc;
        hv_in[(long)n * KP_H + c] = f2bf(v);
    } else {
        hv_in[(long)n * KP_H + c] = 0;
    }
    long gt = (long)n * 320 + c;
    if (gt < 2 * kH) stats[gt] = 0.f;
}

// ---------------- vt = segsum(h, batch) + (cnt+1)*vn, to bf16 padded ----------------
__global__ void vt_k(const float* __restrict__ h, const float* __restrict__ vn,
                     const int* __restrict__ counts, const int* __restrict__ starts,
                     u16* __restrict__ vt_in) {
    int g = blockIdx.x, c = threadIdx.x;  // block = 320
    if (c >= kH) { vt_in[(long)g * KP_H + c] = 0; return; }
    int cnt = counts[g], st = starts[g];
    float acc = 0.f;
    for (int i = 0; i < cnt; i++) acc += h[(long)(st + i) * kH + c];
    acc += (float)(cnt + 1) * vn[g * kH + c];
    vt_in[(long)g * KP_H + c] = f2bf(acc);
}

// ---------------- GEMM: C[M x store] = act(A[M x KP] @ Wt^T + bias) ----------------
template<int ACT, int OUT_BF16, int BN_STATS>
__global__ __launch_bounds__(256) void gemm_k(
    const u16* __restrict__ A, const u16* __restrict__ Wt,
    const float* __restrict__ bias, void* __restrict__ out,
    float* __restrict__ stats,
    int KP, int NN, int out_stride, int store_cols) {
    __shared__ __align__(16) u16 lA[128][40];
    __shared__ __align__(16) u16 lB[64][40];
    __shared__ float sred[64][2];

    const int tid = threadIdx.x;
    const int lane = tid & 63;
    const int wave = tid >> 6;
    const int l16 = lane & 15;
    const int quad = lane >> 4;
    const int wm = (wave & 1) * 64;
    const int wn = (wave >> 1) * 32;
    const long tm = (long)blockIdx.x * 128;
    const int tn = blockIdx.y * 64;

    const int arow = tid >> 2;
    const int acol = (tid & 3) * 8;

    const u16* gA0 = A + (tm + arow) * KP + acol;
    const u16* gA1 = A + (tm + arow + 64) * KP + acol;
    const u16* gB  = Wt + (long)(tn + arow) * KP + acol;

    f32x4_t acc[4][2];
    #pragma unroll
    for (int i = 0; i < 4; i++)
        #pragma unroll
        for (int j = 0; j < 2; j++) acc[i][j] = (f32x4_t){0.f, 0.f, 0.f, 0.f};

    for (int k0 = 0; k0 < KP; k0 += 32) {
        __syncthreads();
        *(uint4*)&lA[arow][acol]      = *(const uint4*)(gA0 + k0);
        *(uint4*)&lA[arow + 64][acol] = *(const uint4*)(gA1 + k0);
        *(uint4*)&lB[arow][acol]      = *(const uint4*)(gB + k0);
        __syncthreads();
        bf16x8_t af[4], bfr[2];
        #pragma unroll
        for (int mt = 0; mt < 4; mt++) af[mt] = *(const bf16x8_t*)&lA[wm + mt * 16 + l16][quad * 8];
        #pragma unroll
        for (int nt = 0; nt < 2; nt++) bfr[nt] = *(const bf16x8_t*)&lB[wn + nt * 16 + l16][quad * 8];
        #pragma unroll
        for (int mt = 0; mt < 4; mt++)
            #pragma unroll
            for (int nt = 0; nt < 2; nt++)
                acc[mt][nt] = __builtin_amdgcn_mfma_f32_16x16x32_bf16(af[mt], bfr[nt], acc[mt][nt], 0, 0, 0);
    }

    if (BN_STATS) {
        if (tid < 64) { sred[tid][0] = 0.f; sred[tid][1] = 0.f; }
    }
    __syncthreads();

    #pragma unroll
    for (int nt = 0; nt < 2; nt++) {
        int col = tn + wn + nt * 16 + l16;
        float bv = (col < NN) ? bias[col] : 0.f;
        float s = 0.f, s2 = 0.f;
        #pragma unroll
        for (int mt = 0; mt < 4; mt++) {
            #pragma unroll
            for (int r = 0; r < 4; r++) {
                long row = tm + wm + mt * 16 + quad * 4 + r;
                float v = acc[mt][nt][r] + bv;
                if (ACT) v = fmaxf(v, 0.f);
                float sv = (col < NN) ? v : 0.f;
                if (col < store_cols) {
                    if (OUT_BF16) ((u16*)out)[row * out_stride + col] = f2bf(sv);
                    else          ((float*)out)[row * out_stride + col] = sv;
                }
                s += sv; s2 += sv * sv;
            }
        }
        if (BN_STATS) {
            atomicAdd(&sred[wn + nt * 16 + l16][0], s);
            atomicAdd(&sred[wn + nt * 16 + l16][1], s2);
        }
    }
    if (BN_STATS) {
        __syncthreads();
        if (tid < 64) {
            int col = tn + tid;
            if (col < NN) {
                atomicAdd(&stats[col], sred[tid][0]);
                atomicAdd(&stats[NN + col], sred[tid][1]);
            }
        }
    }
}

// ---------------- BN-apply + (relu) + residual: h += act(z*a + b); z is bf16 stride KP_H ----------------
template<int RELU>
__global__ void resid_k(float* __restrict__ h, const u16* __restrict__ z,
                        const float* __restrict__ stats, const float* __restrict__ scale,
                        const float* __restrict__ bias, int l) {
    int n = blockIdx.x, c = threadIdx.x;
    if (c >= kH) return;
    float mean = stats[c] * (1.f / (float)kN);
    float var = stats[kH + c] * (1.f / (float)kN) - mean * mean;
    var = fmaxf(var, 0.f);
    float a = scale[l * kH + c] * rsqrtf(var + 1e-5f);
    float b = bias[l * kH + c] - mean * a;
    float v = bf2f(z[(long)n * KP_H + c]) * a + b;
    if (RELU) v = fmaxf(v, 0.f);
    h[(long)n * kH + c] += v;
}

__global__ void vnupd_k(float* __restrict__ vn, const float* __restrict__ z) {
    int g = blockIdx.x, c = threadIdx.x;
    if (c < kH) vn[g * kH + c] += fmaxf(z[g * kH + c], 0.f);
}

// ---------------- pooled mean of h -> h_rep cols [0,300) ----------------
__global__ void pooled_k(const float* __restrict__ h, const int* __restrict__ counts,
                         const int* __restrict__ starts, u16* __restrict__ hrep) {
    int g = blockIdx.x, c = threadIdx.x;
    if (c >= kH) return;
    int cnt = counts[g], st = starts[g];
    float acc = 0.f;
    for (int i = 0; i < cnt; i++) acc += h[(long)(st + i) * kH + c];
    acc /= (float)(cnt > 0 ? cnt : 1);
    hrep[(long)g * KP_DG + c] = f2bf(acc);
}

// ---------------- h_rep cols [300,1536): id_pool | morgan | maccs | zero-pad ----------------
__global__ void hrep_rest_k(const float* __restrict__ morgan, const float* __restrict__ maccs,
                            const int* __restrict__ counts, u16* __restrict__ hrep) {
    long idx = (long)blockIdx.x * 256 + threadIdx.x;
    if (idx >= (long)kG * (KP_DG - kH)) return;
    int g = (int)(idx / (KP_DG - kH));
    int j = (int)(idx % (KP_DG - kH));
    int col = kH + j;
    u16 v;
    if (j < kF) {
        int c = counts[g];
        int q = (j < c) ? ((c - 1 - j) / kF + 1) : 0;  // #k in [0,c) with k%32==j
        v = f2bf((float)q / (float)(c > 0 ? c : 1));
    } else if (j < kF + 1024) {
        v = f2bf(morgan[(long)g * 1024 + (j - kF)]);
    } else if (j < kF + 1024 + 167) {
        v = f2bf(maccs[(long)g * 167 + (j - kF - 1024)]);
    } else {
        v = 0;
    }
    hrep[(long)g * KP_DG + col] = v;
}

// ---------------- final: out[g] = zp[g,:600] . Wp2 + bp2 ----------------
__global__ void final_k(const u16* __restrict__ zp, const float* __restrict__ Wp2,
                        const float* __restrict__ bp2, float* __restrict__ out) {
    int wave = threadIdx.x >> 6, lane = threadIdx.x & 63;
    int g = blockIdx.x * 4 + wave;
    float acc = 0.f;
    for (int c = lane; c < kH2; c += 64) acc += bf2f(zp[(long)g * KP_H2 + c]) * Wp2[c];
    #pragma unroll
    for (int off = 32; off; off >>= 1) acc += __shfl_down(acc, off);
    if (lane == 0) out[g] = acc + bp2[0];
}

extern "C" void kernel_launch(void* const* d_in, const int* in_sizes, int n_in,
                              void* d_out, int out_size, void* d_ws, size_t ws_size,
                              hipStream_t stream) {
    const float* x      = (const float*)d_in[0];
    const float* morgan = (const float*)d_in[1];
    const float* maccs  = (const float*)d_in[2];
    const int*   ei     = (const int*)d_in[3];
    const int*   batch  = (const int*)d_in[4];
    const float* W_emb  = (const float*)d_in[5];
    const float* b_emb  = (const float*)d_in[6];
    const float* gin_W1 = (const float*)d_in[7];
    const float* gin_b1 = (const float*)d_in[8];
    const float* gin_W2 = (const float*)d_in[9];
    const float* gin_b2 = (const float*)d_in[10];
    const float* bn_scale = (const float*)d_in[11];
    const float* bn_bias  = (const float*)d_in[12];
    const float* eps    = (const float*)d_in[13];
    const float* vn0    = (const float*)d_in[14];
    const float* vn_W1  = (const float*)d_in[15];
    const float* vn_b1  = (const float*)d_in[16];
    const float* vn_W2  = (const float*)d_in[17];
    const float* vn_b2  = (const float*)d_in[18];
    const float* Wp1    = (const float*)d_in[19];
    const float* bp1    = (const float*)d_in[20];
    const float* Wp2    = (const float*)d_in[21];
    const float* bp2    = (const float*)d_in[22];
    float* out = (float*)d_out;

    char* ws = (char*)d_ws;
    size_t off = 0;
    auto alloc = [&](size_t bytes) -> char* {
        char* p = ws + off;
        off += (bytes + 255) & ~(size_t)255;
        return p;
    };
    float* h   = (float*)alloc((size_t)kN * kH * 4);       // 78.6 MB
    u16*   hv  = (u16*)alloc((size_t)kN * KP_H * 2);       // 41.9 MB  (hv_in, then z2 bf16)
    char*  S   = alloc((size_t)C_ROWS * KP_H2 * 2);        // 10.0 MB scratch region
    float* vn  = (float*)alloc((size_t)kG * kH * 4);       // 2.5 MB
    int* counts = (int*)alloc(kG * 4);
    int* starts = (int*)alloc(kG * 4);
    float* stats = (float*)alloc(2 * kH * 4);
    int* cnt_n  = (int*)alloc((size_t)kN * 4);
    int* start_n = (int*)alloc((size_t)(kN + 1) * 4);
    int* fill_n = (int*)alloc((size_t)kN * 4);
    int* perm   = (int*)alloc((size_t)kE * 4);
    u16* Wt_g1 = (u16*)alloc((size_t)kL * NP_H2 * KP_H * 2);
    u16* Wt_g2 = (u16*)alloc((size_t)kL * NP_H * KP_H2 * 2);
    u16* Wt_v1 = (u16*)alloc((size_t)(kL - 1) * NP_H2 * KP_H * 2);
    u16* Wt_v2 = (u16*)alloc((size_t)(kL - 1) * NP_H * KP_H2 * 2);
    u16* Wt_p1 = (u16*)alloc((size_t)NP_H2 * KP_DG * 2);
    if (off > ws_size) return;  // ~140 MB required

    // scratch-region sub-buffers (lifetimes don't overlap z1 chunks):
    u16*   z1c   = (u16*)S;                                  // [C_ROWS, 608] bf16
    u16*   vt_in = (u16*)S;                                  // [2048, 320] bf16
    u16*   z1v   = (u16*)(S + (size_t)kG * KP_H * 2);        // [2048, 608] bf16
    float* z2v   = (float*)(S + (size_t)kG * (KP_H + KP_H2) * 2);  // [2048, 300] f32
    u16*   hrep  = (u16*)S;                                  // [2048, 1536] bf16
    u16*   zp    = (u16*)(S + (size_t)kG * KP_DG * 2);       // [2048, 608] bf16

    // weight transposes (f32 -> padded bf16)
    {
        long t1 = (long)kL * NP_H2 * KP_H;
        transpose_k<<<dim3((unsigned)((t1 + 255) / 256)), 256, 0, stream>>>(gin_W1, Wt_g1, kH, kH2, NP_H2, KP_H, t1);
        long t2 = (long)kL * NP_H * KP_H2;
        transpose_k<<<dim3((unsigned)((t2 + 255) / 256)), 256, 0, stream>>>(gin_W2, Wt_g2, kH2, kH, NP_H, KP_H2, t2);
        long t3 = (long)(kL - 1) * NP_H2 * KP_H;
        transpose_k<<<dim3((unsigned)((t3 + 255) / 256)), 256, 0, stream>>>(vn_W1, Wt_v1, kH, kH2, NP_H2, KP_H, t3);
        long t4 = (long)(kL - 1) * NP_H * KP_H2;
        transpose_k<<<dim3((unsigned)((t4 + 255) / 256)), 256, 0, stream>>>(vn_W2, Wt_v2, kH2, kH, NP_H, KP_H2, t4);
        long t5 = (long)NP_H2 * KP_DG;
        transpose_k<<<dim3((unsigned)((t5 + 255) / 256)), 256, 0, stream>>>(Wp1, Wt_p1, kDG, kH2, NP_H2, KP_DG, t5);
    }

    // graph ranges + node CSR
    hipMemsetAsync(counts, 0, kG * 4, stream);
    hipMemsetAsync(cnt_n, 0, (size_t)kN * 4, stream);
    hipMemsetAsync(fill_n, 0, (size_t)kN * 4, stream);
    hist_g_k<<<kN / 256, 256, 0, stream>>>(batch, counts);
    scan_g_k<<<1, 1024, 0, stream>>>(counts, starts);
    hist_n_k<<<kE / 256, 256, 0, stream>>>(ei, cnt_n);
    scan_n_k<<<1, 1024, 0, stream>>>(cnt_n, start_n);
    fill_n_k<<<kE / 256, 256, 0, stream>>>(ei, start_n, fill_n, perm);

    embed_k<<<kN, 320, 0, stream>>>(x, W_emb, b_emb, h);
    vninit_k<<<kG, 320, 0, stream>>>(vn0, vn);

    for (int l = 0; l < kL; l++) {
        gather_combine_k<<<kN, 320, 0, stream>>>(h, vn, batch, start_n, perm, eps, l, hv, stats);
        if (l < kL - 1) {
            // virtual-node path first (uses pre-residual h, old vn; S region free)
            vt_k<<<kG, 320, 0, stream>>>(h, vn, counts, starts, vt_in);
            gemm_k<1, 1, 0><<<dim3(16, 10), 256, 0, stream>>>(
                vt_in, Wt_v1 + (size_t)l * NP_H2 * KP_H, vn_b1 + l * kH2,
                z1v, nullptr, KP_H, kH2, KP_H2, KP_H2);
            gemm_k<0, 0, 0><<<dim3(16, 5), 256, 0, stream>>>(
                z1v, Wt_v2 + (size_t)l * NP_H * KP_H2, vn_b2 + l * kH,
                z2v, nullptr, KP_H2, kH, kH, kH);
            vnupd_k<<<kG, 320, 0, stream>>>(vn, z2v);
        }
        // node MLP in M-chunks; z2 (bf16) overwrites hv rows in place
        for (int c = 0; c < C_CHUNK; c++) {
            const u16* Ain = hv + (size_t)c * C_ROWS * KP_H;
            gemm_k<1, 1, 0><<<dim3(C_ROWS / 128, 10), 256, 0, stream>>>(
                Ain, Wt_g1 + (size_t)l * NP_H2 * KP_H, gin_b1 + l * kH2,
                z1c, nullptr, KP_H, kH2, KP_H2, KP_H2);
            gemm_k<0, 1, 1><<<dim3(C_ROWS / 128, 5), 256, 0, stream>>>(
                z1c, Wt_g2 + (size_t)l * NP_H * KP_H2, gin_b2 + l * kH,
                (void*)(hv + (size_t)c * C_ROWS * KP_H), stats, KP_H2, kH, KP_H, kH);
        }
        if (l < kL - 1)
            resid_k<1><<<kN, 320, 0, stream>>>(h, hv, stats, bn_scale, bn_bias, l);
        else
            resid_k<0><<<kN, 320, 0, stream>>>(h, hv, stats, bn_scale, bn_bias, l);
    }

    pooled_k<<<kG, 320, 0, stream>>>(h, counts, starts, hrep);
    {
        long tr = (long)kG * (KP_DG - kH);
        hrep_rest_k<<<dim3((unsigned)((tr + 255) / 256)), 256, 0, stream>>>(morgan, maccs, counts, hrep);
    }
    gemm_k<1, 1, 0><<<dim3(16, 10), 256, 0, stream>>>(
        hrep, Wt_p1, bp1, zp, nullptr, KP_DG, kH2, KP_H2, KP_H2);
    final_k<<<kG / 4, 256, 0, stream>>>(zp, Wp2, bp2, out);
}

// Round 4
// 2198.848 us; speedup vs baseline: 1.2363x; 1.2363x over previous
//
#include <hip/hip_runtime.h>

typedef unsigned short u16;
typedef unsigned int u32;
typedef __attribute__((ext_vector_type(8))) short bf16x8_t;
typedef __attribute__((ext_vector_type(4))) float f32x4_t;

// problem constants
#define kN 65536
#define kE 262144
#define kG 2048
#define kH 300
#define kH2 600
#define kL 5
#define kF 32
#define kDG 1523
// padded dims
#define KP_H 320
#define KP_H2 608
#define KP_DG 1536
#define NP_H2 640
#define NP_H 320
// M-chunking for node MLP
#define C_CHUNK 4
#define C_ROWS (kN / C_CHUNK)   // 16384
// per-graph accumulator row stride (floats)
#define PGS 304

__device__ __forceinline__ float bf2f(u16 x) {
    union { u32 u; float f; } v; v.u = ((u32)x) << 16; return v.f;
}
__device__ __forceinline__ u16 f2bf(float f) {
    union { float f; u32 u; } v; v.f = f;
    u32 u = v.u;
    u32 r = (u + 0x7fffu + ((u >> 16) & 1u)) >> 16;  // RNE
    return (u16)r;
}

// ---------------- weight transpose: W[b][k][n] (f32) -> Wt[b][n][k] (bf16), zero-padded ----------------
__global__ void transpose_k(const float* __restrict__ W, u16* __restrict__ Wt,
                            int K, int NN, int NP, int KP, long total) {
    long idx = (long)blockIdx.x * 256 + threadIdx.x;
    if (idx >= total) return;
    int per = NP * KP;
    int b = (int)(idx / per);
    int r = (int)(idx % per);
    int n = r / KP;
    int k = r % KP;
    u16 v = 0;
    if (n < NN && k < K) v = f2bf(W[(long)b * K * NN + (long)k * NN + n]);
    Wt[idx] = v;
}

// ---------------- graph histogram + scan (G=2048) ----------------
__global__ void hist_g_k(const int* __restrict__ batch, int* __restrict__ counts) {
    int n = blockIdx.x * 256 + threadIdx.x;
    if (n < kN) atomicAdd(&counts[batch[n]], 1);
}

__global__ void scan_g_k(const int* __restrict__ counts, int* __restrict__ starts) {
    __shared__ int s[1024];
    int t = threadIdx.x;
    int c0 = counts[2 * t], c1 = counts[2 * t + 1];
    s[t] = c0 + c1;
    __syncthreads();
    for (int off = 1; off < 1024; off <<= 1) {
        int v = (t >= off) ? s[t - off] : 0;
        __syncthreads();
        s[t] += v;
        __syncthreads();
    }
    int excl = (t > 0) ? s[t - 1] : 0;
    starts[2 * t] = excl;
    starts[2 * t + 1] = excl + c0;
}

// ---------------- node CSR build (dst-sorted edges), 3-phase scan ----------------
__global__ void hist_n_k(const int* __restrict__ ei, int* __restrict__ cnt) {
    int e = blockIdx.x * 256 + threadIdx.x;
    if (e < kE) atomicAdd(&cnt[ei[kE + e]], 1);  // dst
}

__global__ void scanA_k(const int* __restrict__ cnt, int* __restrict__ start, int* __restrict__ bsum) {
    __shared__ int s[1024];
    int b = blockIdx.x, t = threadIdx.x;
    int v = cnt[b * 1024 + t];
    s[t] = v;
    __syncthreads();
    for (int off = 1; off < 1024; off <<= 1) {
        int u = (t >= off) ? s[t - off] : 0;
        __syncthreads();
        s[t] += u;
        __syncthreads();
    }
    start[b * 1024 + t] = s[t] - v;  // block-local exclusive
    if (t == 1023) bsum[b] = s[1023];
}

__global__ void scanB_k(int* __restrict__ bsum) {
    if (threadIdx.x == 0) {
        int s = 0;
        for (int i = 0; i < kN / 1024; i++) { s += bsum[i]; bsum[i] = s; }  // inclusive
    }
}

__global__ void scanC_k(int* __restrict__ start, const int* __restrict__ bsum) {
    int b = blockIdx.x, t = threadIdx.x;
    int add = (b > 0) ? bsum[b - 1] : 0;
    start[b * 1024 + t] += add;
    if (b == kN / 1024 - 1 && t == 1023) start[kN] = bsum[kN / 1024 - 1];
}

__global__ void fill_n_k(const int* __restrict__ ei, const int* __restrict__ start,
                         int* __restrict__ fill, int* __restrict__ perm) {
    int e = blockIdx.x * 256 + threadIdx.x;
    if (e >= kE) return;
    int s = ei[e], d = ei[kE + e];
    int pos = start[d] + atomicAdd(&fill[d], 1);
    perm[pos] = s;
}

// ---------------- node embedding: h = x @ W_emb + b_emb (also bf16 copy) ----------------
__global__ void embed_k(const float* __restrict__ x, const float* __restrict__ W,
                        const float* __restrict__ b, float* __restrict__ h,
                        u16* __restrict__ hbf) {
    int n = blockIdx.x, j = threadIdx.x;
    if (j >= kH) return;
    float acc = b[j];
    #pragma unroll
    for (int d = 0; d < 9; d++) acc += x[n * 9 + d] * W[d * kH + j];
    h[(long)n * kH + j] = acc;
    hbf[(long)n * kH + j] = f2bf(acc);
}

__global__ void vninit_k(const float* __restrict__ vn0, float* __restrict__ vn) {
    int g = blockIdx.x, c = threadIdx.x;
    if (c < kH) vn[g * kH + c] = vn0[c];
}

// ---------------- fused gather + combine (+optional vt accumulation):
//   hvn = h[n]+vn[g]; acc = sum_{e in CSR(n)} (h[src]+vn[g_src]) (bf16 h)
//   hv_in[n] = bf16((1+eps)*hvn + acc); DO_VT: vtacc[g] += hvn; zero stats
template<int DO_VT>
__global__ void gather_combine_k(const u16* __restrict__ hbf, const float* __restrict__ vn,
                                 const int* __restrict__ batch, const int* __restrict__ start_n,
                                 const int* __restrict__ perm, const float* __restrict__ eps,
                                 int l, u16* __restrict__ hv_in, float* __restrict__ stats,
                                 float* __restrict__ vtacc) {
    __shared__ int s_src[64];
    __shared__ int s_g[64];
    int n = blockIdx.x, c = threadIdx.x;  // block = 320
    int st = start_n[n], en = start_n[n + 1];
    float acc = 0.f;
    for (int base = st; base < en; base += 64) {
        int m = min(64, en - base);
        __syncthreads();
        if (c < m) { int s = perm[base + c]; s_src[c] = s; s_g[c] = batch[s]; }
        __syncthreads();
        if (c < kH) {
            int e = 0;
            for (; e + 4 <= m; e += 4) {
                float a0 = bf2f(hbf[(long)s_src[e] * kH + c])     + vn[s_g[e] * kH + c];
                float a1 = bf2f(hbf[(long)s_src[e + 1] * kH + c]) + vn[s_g[e + 1] * kH + c];
                float a2 = bf2f(hbf[(long)s_src[e + 2] * kH + c]) + vn[s_g[e + 2] * kH + c];
                float a3 = bf2f(hbf[(long)s_src[e + 3] * kH + c]) + vn[s_g[e + 3] * kH + c];
                acc += (a0 + a1) + (a2 + a3);
            }
            for (; e < m; e++)
                acc += bf2f(hbf[(long)s_src[e] * kH + c]) + vn[s_g[e] * kH + c];
        }
    }
    if (c < kH) {
        int g = batch[n];
        float hvn = bf2f(hbf[(long)n * kH + c]) + vn[g * kH + c];
        if (DO_VT) atomicAdd(&vtacc[g * PGS + c], hvn);
        float v = (1.f + eps[l]) * hvn + acc;
        hv_in[(long)n * KP_H + c] = f2bf(v);
    } else {
        hv_in[(long)n * KP_H + c] = 0;
    }
    long gt = (long)n * 320 + c;
    if (gt < 2 * kH) stats[gt] = 0.f;
}

// ---------------- vt_in = bf16(vtacc + vn), padded ----------------
__global__ void vt_fin_k(const float* __restrict__ vtacc, const float* __restrict__ vn,
                         u16* __restrict__ vt_in) {
    int g = blockIdx.x, c = threadIdx.x;
    vt_in[(long)g * KP_H + c] = (c < kH) ? f2bf(vtacc[g * PGS + c] + vn[g * kH + c]) : (u16)0;
}

// ---------------- GEMM: C[M x store] = act(A[M x KP] @ Wt^T + bias) ----------------
template<int ACT, int OUT_BF16, int BN_STATS>
__global__ __launch_bounds__(256) void gemm_k(
    const u16* __restrict__ A, const u16* __restrict__ Wt,
    const float* __restrict__ bias, void* __restrict__ out,
    float* __restrict__ stats,
    int KP, int NN, int out_stride, int store_cols) {
    __shared__ __align__(16) u16 lA[128][40];
    __shared__ __align__(16) u16 lB[64][40];
    __shared__ float sred[64][2];

    const int tid = threadIdx.x;
    const int lane = tid & 63;
    const int wave = tid >> 6;
    const int l16 = lane & 15;
    const int quad = lane >> 4;
    const int wm = (wave & 1) * 64;
    const int wn = (wave >> 1) * 32;
    const long tm = (long)blockIdx.x * 128;
    const int tn = blockIdx.y * 64;

    const int arow = tid >> 2;
    const int acol = (tid & 3) * 8;

    const u16* gA0 = A + (tm + arow) * KP + acol;
    const u16* gA1 = A + (tm + arow + 64) * KP + acol;
    const u16* gB  = Wt + (long)(tn + arow) * KP + acol;

    f32x4_t acc[4][2];
    #pragma unroll
    for (int i = 0; i < 4; i++)
        #pragma unroll
        for (int j = 0; j < 2; j++) acc[i][j] = (f32x4_t){0.f, 0.f, 0.f, 0.f};

    for (int k0 = 0; k0 < KP; k0 += 32) {
        __syncthreads();
        *(uint4*)&lA[arow][acol]      = *(const uint4*)(gA0 + k0);
        *(uint4*)&lA[arow + 64][acol] = *(const uint4*)(gA1 + k0);
        *(uint4*)&lB[arow][acol]      = *(const uint4*)(gB + k0);
        __syncthreads();
        bf16x8_t af[4], bfr[2];
        #pragma unroll
        for (int mt = 0; mt < 4; mt++) af[mt] = *(const bf16x8_t*)&lA[wm + mt * 16 + l16][quad * 8];
        #pragma unroll
        for (int nt = 0; nt < 2; nt++) bfr[nt] = *(const bf16x8_t*)&lB[wn + nt * 16 + l16][quad * 8];
        #pragma unroll
        for (int mt = 0; mt < 4; mt++)
            #pragma unroll
            for (int nt = 0; nt < 2; nt++)
                acc[mt][nt] = __builtin_amdgcn_mfma_f32_16x16x32_bf16(af[mt], bfr[nt], acc[mt][nt], 0, 0, 0);
    }

    if (BN_STATS) {
        if (tid < 64) { sred[tid][0] = 0.f; sred[tid][1] = 0.f; }
    }
    __syncthreads();

    #pragma unroll
    for (int nt = 0; nt < 2; nt++) {
        int col = tn + wn + nt * 16 + l16;
        float bv = (col < NN) ? bias[col] : 0.f;
        float s = 0.f, s2 = 0.f;
        #pragma unroll
        for (int mt = 0; mt < 4; mt++) {
            #pragma unroll
            for (int r = 0; r < 4; r++) {
                long row = tm + wm + mt * 16 + quad * 4 + r;
                float v = acc[mt][nt][r] + bv;
                if (ACT) v = fmaxf(v, 0.f);
                float sv = (col < NN) ? v : 0.f;
                if (col < store_cols) {
                    if (OUT_BF16) ((u16*)out)[row * out_stride + col] = f2bf(sv);
                    else          ((float*)out)[row * out_stride + col] = sv;
                }
                s += sv; s2 += sv * sv;
            }
        }
        if (BN_STATS) {
            atomicAdd(&sred[wn + nt * 16 + l16][0], s);
            atomicAdd(&sred[wn + nt * 16 + l16][1], s2);
        }
    }
    if (BN_STATS) {
        __syncthreads();
        if (tid < 64) {
            int col = tn + tid;
            if (col < NN) {
                atomicAdd(&stats[col], sred[tid][0]);
                atomicAdd(&stats[NN + col], sred[tid][1]);
            }
        }
    }
}

// ---------------- BN-apply + (relu) + residual; maintains h_bf; optional pool accumulate ----------------
template<int RELU, int POOL>
__global__ void resid_k(float* __restrict__ h, u16* __restrict__ hbf,
                        const u16* __restrict__ z, const float* __restrict__ stats,
                        const float* __restrict__ scale, const float* __restrict__ bias, int l,
                        const int* __restrict__ batch, float* __restrict__ poolacc) {
    int n = blockIdx.x, c = threadIdx.x;
    if (c >= kH) return;
    float mean = stats[c] * (1.f / (float)kN);
    float var = stats[kH + c] * (1.f / (float)kN) - mean * mean;
    var = fmaxf(var, 0.f);
    float a = scale[l * kH + c] * rsqrtf(var + 1e-5f);
    float b = bias[l * kH + c] - mean * a;
    float v = bf2f(z[(long)n * KP_H + c]) * a + b;
    if (RELU) v = fmaxf(v, 0.f);
    float hn = h[(long)n * kH + c] + v;
    h[(long)n * kH + c] = hn;
    hbf[(long)n * kH + c] = f2bf(hn);
    if (POOL) atomicAdd(&poolacc[batch[n] * PGS + c], hn);
}

__global__ void vnupd_k(float* __restrict__ vn, const float* __restrict__ z) {
    int g = blockIdx.x, c = threadIdx.x;
    if (c < kH) vn[g * kH + c] += fmaxf(z[g * kH + c], 0.f);
}

// ---------------- h_rep cols [0,300): pooled mean from poolacc ----------------
__global__ void pooled_fin_k(const float* __restrict__ poolacc, const int* __restrict__ counts,
                             u16* __restrict__ hrep) {
    int g = blockIdx.x, c = threadIdx.x;
    if (c >= kH) return;
    int cnt = counts[g];
    hrep[(long)g * KP_DG + c] = f2bf(poolacc[g * PGS + c] / (float)(cnt > 0 ? cnt : 1));
}

// ---------------- h_rep cols [300,1536): id_pool | morgan | maccs | zero-pad ----------------
__global__ void hrep_rest_k(const float* __restrict__ morgan, const float* __restrict__ maccs,
                            const int* __restrict__ counts, u16* __restrict__ hrep) {
    long idx = (long)blockIdx.x * 256 + threadIdx.x;
    if (idx >= (long)kG * (KP_DG - kH)) return;
    int g = (int)(idx / (KP_DG - kH));
    int j = (int)(idx % (KP_DG - kH));
    int col = kH + j;
    u16 v;
    if (j < kF) {
        int c = counts[g];
        int q = (j < c) ? ((c - 1 - j) / kF + 1) : 0;  // #k in [0,c) with k%32==j
        v = f2bf((float)q / (float)(c > 0 ? c : 1));
    } else if (j < kF + 1024) {
        v = f2bf(morgan[(long)g * 1024 + (j - kF)]);
    } else if (j < kF + 1024 + 167) {
        v = f2bf(maccs[(long)g * 167 + (j - kF - 1024)]);
    } else {
        v = 0;
    }
    hrep[(long)g * KP_DG + col] = v;
}

// ---------------- final: out[g] = zp[g,:600] . Wp2 + bp2 ----------------
__global__ void final_k(const u16* __restrict__ zp, const float* __restrict__ Wp2,
                        const float* __restrict__ bp2, float* __restrict__ out) {
    int wave = threadIdx.x >> 6, lane = threadIdx.x & 63;
    int g = blockIdx.x * 4 + wave;
    float acc = 0.f;
    for (int c = lane; c < kH2; c += 64) acc += bf2f(zp[(long)g * KP_H2 + c]) * Wp2[c];
    #pragma unroll
    for (int off = 32; off; off >>= 1) acc += __shfl_down(acc, off);
    if (lane == 0) out[g] = acc + bp2[0];
}

extern "C" void kernel_launch(void* const* d_in, const int* in_sizes, int n_in,
                              void* d_out, int out_size, void* d_ws, size_t ws_size,
                              hipStream_t stream) {
    const float* x      = (const float*)d_in[0];
    const float* morgan = (const float*)d_in[1];
    const float* maccs  = (const float*)d_in[2];
    const int*   ei     = (const int*)d_in[3];
    const int*   batch  = (const int*)d_in[4];
    const float* W_emb  = (const float*)d_in[5];
    const float* b_emb  = (const float*)d_in[6];
    const float* gin_W1 = (const float*)d_in[7];
    const float* gin_b1 = (const float*)d_in[8];
    const float* gin_W2 = (const float*)d_in[9];
    const float* gin_b2 = (const float*)d_in[10];
    const float* bn_scale = (const float*)d_in[11];
    const float* bn_bias  = (const float*)d_in[12];
    const float* eps    = (const float*)d_in[13];
    const float* vn0    = (const float*)d_in[14];
    const float* vn_W1  = (const float*)d_in[15];
    const float* vn_b1  = (const float*)d_in[16];
    const float* vn_W2  = (const float*)d_in[17];
    const float* vn_b2  = (const float*)d_in[18];
    const float* Wp1    = (const float*)d_in[19];
    const float* bp1    = (const float*)d_in[20];
    const float* Wp2    = (const float*)d_in[21];
    const float* bp2    = (const float*)d_in[22];
    float* out = (float*)d_out;

    char* ws = (char*)d_ws;
    size_t off = 0;
    auto alloc = [&](size_t bytes) -> char* {
        char* p = ws + off;
        off += (bytes + 255) & ~(size_t)255;
        return p;
    };
    float* h    = (float*)alloc((size_t)kN * kH * 4);       // 78.6 MB
    u16*   hbf  = (u16*)alloc((size_t)kN * kH * 2);         // 39.3 MB bf16 copy of h
    u16*   hv   = (u16*)alloc((size_t)kN * KP_H * 2);       // 41.9 MB (hv_in, then z2 bf16)
    char*  S    = alloc((size_t)C_ROWS * KP_H2 * 2);        // 19.9 MB scratch region
    float* vn   = (float*)alloc((size_t)kG * kH * 4);       // 2.5 MB
    int* counts = (int*)alloc(kG * 4);
    int* starts = (int*)alloc(kG * 4);
    float* stats = (float*)alloc(2 * kH * 4);
    int* cnt_n  = (int*)alloc((size_t)kN * 4);
    int* start_n = (int*)alloc((size_t)(kN + 1) * 4);
    int* fill_n = (int*)alloc((size_t)kN * 4);
    int* bsum   = (int*)alloc((kN / 1024) * 4);
    int* perm   = (int*)alloc((size_t)kE * 4);
    u16* Wt_g1 = (u16*)alloc((size_t)kL * NP_H2 * KP_H * 2);
    u16* Wt_g2 = (u16*)alloc((size_t)kL * NP_H * KP_H2 * 2);
    u16* Wt_v1 = (u16*)alloc((size_t)(kL - 1) * NP_H2 * KP_H * 2);
    u16* Wt_v2 = (u16*)alloc((size_t)(kL - 1) * NP_H * KP_H2 * 2);
    u16* Wt_p1 = (u16*)alloc((size_t)NP_H2 * KP_DG * 2);
    if (off > ws_size) return;  // ~194 MB required

    // scratch-region overlays (disjoint lifetimes vs z1c chunk buffer):
    u16*   z1c   = (u16*)S;                                        // [16384, 608] bf16 (node chunks)
    u16*   vt_in = (u16*)S;                                        // [2048, 320] bf16
    u16*   z1v   = (u16*)(S + (size_t)kG * KP_H * 2);              // [2048, 608] bf16
    float* z2v   = (float*)(S + (size_t)kG * (KP_H + KP_H2) * 2);  // [2048, 300] f32
    float* vtacc = (float*)(S + 7 * 1024 * 1024);                  // [2048, 304] f32 (pre-chunk phase)
    u16*   hrep  = (u16*)S;                                        // [2048, 1536] bf16 (post-layers)
    u16*   zp    = (u16*)(S + (size_t)kG * KP_DG * 2);             // [2048, 608] bf16
    float* poolacc = (float*)(S + 10 * 1024 * 1024);               // [2048, 304] f32 (last layer)

    // weight transposes (f32 -> padded bf16)
    {
        long t1 = (long)kL * NP_H2 * KP_H;
        transpose_k<<<dim3((unsigned)((t1 + 255) / 256)), 256, 0, stream>>>(gin_W1, Wt_g1, kH, kH2, NP_H2, KP_H, t1);
        long t2 = (long)kL * NP_H * KP_H2;
        transpose_k<<<dim3((unsigned)((t2 + 255) / 256)), 256, 0, stream>>>(gin_W2, Wt_g2, kH2, kH, NP_H, KP_H2, t2);
        long t3 = (long)(kL - 1) * NP_H2 * KP_H;
        transpose_k<<<dim3((unsigned)((t3 + 255) / 256)), 256, 0, stream>>>(vn_W1, Wt_v1, kH, kH2, NP_H2, KP_H, t3);
        long t4 = (long)(kL - 1) * NP_H * KP_H2;
        transpose_k<<<dim3((unsigned)((t4 + 255) / 256)), 256, 0, stream>>>(vn_W2, Wt_v2, kH2, kH, NP_H, KP_H2, t4);
        long t5 = (long)NP_H2 * KP_DG;
        transpose_k<<<dim3((unsigned)((t5 + 255) / 256)), 256, 0, stream>>>(Wp1, Wt_p1, kDG, kH2, NP_H2, KP_DG, t5);
    }

    // graph ranges + node CSR
    hipMemsetAsync(counts, 0, kG * 4, stream);
    hipMemsetAsync(cnt_n, 0, (size_t)kN * 4, stream);
    hipMemsetAsync(fill_n, 0, (size_t)kN * 4, stream);
    hist_g_k<<<kN / 256, 256, 0, stream>>>(batch, counts);
    scan_g_k<<<1, 1024, 0, stream>>>(counts, starts);
    hist_n_k<<<kE / 256, 256, 0, stream>>>(ei, cnt_n);
    scanA_k<<<kN / 1024, 1024, 0, stream>>>(cnt_n, start_n, bsum);
    scanB_k<<<1, 64, 0, stream>>>(bsum);
    scanC_k<<<kN / 1024, 1024, 0, stream>>>(start_n, bsum);
    fill_n_k<<<kE / 256, 256, 0, stream>>>(ei, start_n, fill_n, perm);

    embed_k<<<kN, 320, 0, stream>>>(x, W_emb, b_emb, h, hbf);
    vninit_k<<<kG, 320, 0, stream>>>(vn0, vn);

    for (int l = 0; l < kL; l++) {
        if (l < kL - 1) {
            hipMemsetAsync(vtacc, 0, (size_t)kG * PGS * 4, stream);
            gather_combine_k<1><<<kN, 320, 0, stream>>>(hbf, vn, batch, start_n, perm, eps, l, hv, stats, vtacc);
            vt_fin_k<<<kG, 320, 0, stream>>>(vtacc, vn, vt_in);
            gemm_k<1, 1, 0><<<dim3(16, 10), 256, 0, stream>>>(
                vt_in, Wt_v1 + (size_t)l * NP_H2 * KP_H, vn_b1 + l * kH2,
                z1v, nullptr, KP_H, kH2, KP_H2, KP_H2);
            gemm_k<0, 0, 0><<<dim3(16, 5), 256, 0, stream>>>(
                z1v, Wt_v2 + (size_t)l * NP_H * KP_H2, vn_b2 + l * kH,
                z2v, nullptr, KP_H2, kH, kH, kH);
            vnupd_k<<<kG, 320, 0, stream>>>(vn, z2v);
        } else {
            gather_combine_k<0><<<kN, 320, 0, stream>>>(hbf, vn, batch, start_n, perm, eps, l, hv, stats, nullptr);
        }
        // node MLP in M-chunks; z2 (bf16) overwrites hv rows in place
        for (int c = 0; c < C_CHUNK; c++) {
            const u16* Ain = hv + (size_t)c * C_ROWS * KP_H;
            gemm_k<1, 1, 0><<<dim3(C_ROWS / 128, 10), 256, 0, stream>>>(
                Ain, Wt_g1 + (size_t)l * NP_H2 * KP_H, gin_b1 + l * kH2,
                z1c, nullptr, KP_H, kH2, KP_H2, KP_H2);
            gemm_k<0, 1, 1><<<dim3(C_ROWS / 128, 5), 256, 0, stream>>>(
                z1c, Wt_g2 + (size_t)l * NP_H * KP_H2, gin_b2 + l * kH,
                (void*)(hv + (size_t)c * C_ROWS * KP_H), stats, KP_H2, kH, KP_H, kH);
        }
        if (l < kL - 1) {
            resid_k<1, 0><<<kN, 320, 0, stream>>>(h, hbf, hv, stats, bn_scale, bn_bias, l, batch, nullptr);
        } else {
            hipMemsetAsync(poolacc, 0, (size_t)kG * PGS * 4, stream);
            resid_k<0, 1><<<kN, 320, 0, stream>>>(h, hbf, hv, stats, bn_scale, bn_bias, l, batch, poolacc);
        }
    }

    pooled_fin_k<<<kG, 320, 0, stream>>>(poolacc, counts, hrep);
    {
        long tr = (long)kG * (KP_DG - kH);
        hrep_rest_k<<<dim3((unsigned)((tr + 255) / 256)), 256, 0, stream>>>(morgan, maccs, counts, hrep);
    }
    gemm_k<1, 1, 0><<<dim3(16, 10), 256, 0, stream>>>(
        hrep, Wt_p1, bp1, zp, nullptr, KP_DG, kH2, KP_H2, KP_H2);
    final_k<<<kG / 4, 256, 0, stream>>>(zp, Wp2, bp2, out);
}

// Round 5
// 2028.615 us; speedup vs baseline: 1.3400x; 1.0839x over previous
//
#include <hip/hip_runtime.h>

typedef unsigned short u16;
typedef unsigned int u32;
typedef __attribute__((ext_vector_type(8))) short bf16x8_t;
typedef __attribute__((ext_vector_type(4))) float f32x4_t;

// problem constants
#define kN 65536
#define kE 262144
#define kG 2048
#define kH 300
#define kH2 600
#define kL 5
#define kF 32
#define kDG 1523
// padded dims (all K multiples of 64)
#define KP_H 320
#define KP_H2 640
#define KP_DG 1536
#define NP_H2 640
#define NP_H 320
// M-chunking for node MLP
#define C_CHUNK 4
#define C_ROWS (kN / C_CHUNK)   // 16384

__device__ __forceinline__ float bf2f(u16 x) {
    union { u32 u; float f; } v; v.u = ((u32)x) << 16; return v.f;
}
__device__ __forceinline__ u16 f2bf(float f) {
    union { float f; u32 u; } v; v.f = f;
    u32 u = v.u;
    u32 r = (u + 0x7fffu + ((u >> 16) & 1u)) >> 16;  // RNE
    return (u16)r;
}

// ---------------- weight transpose: W[b][k][n] (f32) -> Wt[b][n][k] (bf16), zero-padded ----------------
__global__ void transpose_k(const float* __restrict__ W, u16* __restrict__ Wt,
                            int K, int NN, int NP, int KP, long total) {
    long idx = (long)blockIdx.x * 256 + threadIdx.x;
    if (idx >= total) return;
    int per = NP * KP;
    int b = (int)(idx / per);
    int r = (int)(idx % per);
    int n = r / KP;
    int k = r % KP;
    u16 v = 0;
    if (n < NN && k < K) v = f2bf(W[(long)b * K * NN + (long)k * NN + n]);
    Wt[idx] = v;
}

// ---------------- graph histogram + scan (G=2048) ----------------
__global__ void hist_g_k(const int* __restrict__ batch, int* __restrict__ counts) {
    int n = blockIdx.x * 256 + threadIdx.x;
    if (n < kN) atomicAdd(&counts[batch[n]], 1);
}

__global__ void scan_g_k(const int* __restrict__ counts, int* __restrict__ starts) {
    __shared__ int s[1024];
    int t = threadIdx.x;
    int c0 = counts[2 * t], c1 = counts[2 * t + 1];
    s[t] = c0 + c1;
    __syncthreads();
    for (int off = 1; off < 1024; off <<= 1) {
        int v = (t >= off) ? s[t - off] : 0;
        __syncthreads();
        s[t] += v;
        __syncthreads();
    }
    int excl = (t > 0) ? s[t - 1] : 0;
    starts[2 * t] = excl;
    starts[2 * t + 1] = excl + c0;
}

// ---------------- node CSR build (dst-sorted edges), 3-phase scan ----------------
__global__ void hist_n_k(const int* __restrict__ ei, int* __restrict__ cnt) {
    int e = blockIdx.x * 256 + threadIdx.x;
    if (e < kE) atomicAdd(&cnt[ei[kE + e]], 1);  // dst
}

__global__ void scanA_k(const int* __restrict__ cnt, int* __restrict__ start, int* __restrict__ bsum) {
    __shared__ int s[1024];
    int b = blockIdx.x, t = threadIdx.x;
    int v = cnt[b * 1024 + t];
    s[t] = v;
    __syncthreads();
    for (int off = 1; off < 1024; off <<= 1) {
        int u = (t >= off) ? s[t - off] : 0;
        __syncthreads();
        s[t] += u;
        __syncthreads();
    }
    start[b * 1024 + t] = s[t] - v;  // block-local exclusive
    if (t == 1023) bsum[b] = s[1023];
}

__global__ void scanB_k(int* __restrict__ bsum) {
    if (threadIdx.x == 0) {
        int s = 0;
        for (int i = 0; i < kN / 1024; i++) { s += bsum[i]; bsum[i] = s; }  // inclusive
    }
}

__global__ void scanC_k(int* __restrict__ start, const int* __restrict__ bsum) {
    int b = blockIdx.x, t = threadIdx.x;
    int add = (b > 0) ? bsum[b - 1] : 0;
    start[b * 1024 + t] += add;
    if (b == kN / 1024 - 1 && t == 1023) start[kN] = bsum[kN / 1024 - 1];
}

__global__ void fill_n_k(const int* __restrict__ ei, const int* __restrict__ start,
                         int* __restrict__ fill, int* __restrict__ perm) {
    int e = blockIdx.x * 256 + threadIdx.x;
    if (e >= kE) return;
    int s = ei[e], d = ei[kE + e];
    int pos = start[d] + atomicAdd(&fill[d], 1);
    perm[pos] = s;
}

// ---------------- node embedding: h = x @ W_emb + b_emb ----------------
__global__ void embed_k(const float* __restrict__ x, const float* __restrict__ W,
                        const float* __restrict__ b, float* __restrict__ h) {
    int n = blockIdx.x, j = threadIdx.x;
    if (j >= kH) return;
    float acc = b[j];
    #pragma unroll
    for (int d = 0; d < 9; d++) acc += x[n * 9 + d] * W[d * kH + j];
    h[(long)n * kH + j] = acc;
}

__global__ void vninit_k(const float* __restrict__ vn0, float* __restrict__ vn) {
    int g = blockIdx.x, c = threadIdx.x;
    if (c < kH) vn[g * kH + c] = vn0[c];
}

// hvbf[n] = bf16(h[n] + vn0[c])  (layer-0 init; vn identical across graphs)
__global__ void hv0_k(const float* __restrict__ h, const float* __restrict__ vn0,
                      u16* __restrict__ hvbf) {
    int n = blockIdx.x, c = threadIdx.x;
    if (c < kH) hvbf[(long)n * kH + c] = f2bf(h[(long)n * kH + c] + vn0[c]);
}

// ---------------- gather + combine: hv_in[n] = bf16((1+eps)*hvbf[n] + sum_e hvbf[src_e]) ----------------
// no barriers; perm[] loads are block-uniform (scalarized); zero K-pad; zero stats
__global__ void gather_combine_k(const u16* __restrict__ hvbf, const int* __restrict__ start_n,
                                 const int* __restrict__ perm, const float* __restrict__ eps,
                                 int l, u16* __restrict__ hv_in, float* __restrict__ stats) {
    int n = blockIdx.x, c = threadIdx.x;  // block = 320
    int st = start_n[n], en = start_n[n + 1];
    float acc = 0.f;
    int e = st;
    for (; e + 4 <= en; e += 4) {
        int s0 = perm[e], s1 = perm[e + 1], s2 = perm[e + 2], s3 = perm[e + 3];
        if (c < kH) {
            float a0 = bf2f(hvbf[(long)s0 * kH + c]);
            float a1 = bf2f(hvbf[(long)s1 * kH + c]);
            float a2 = bf2f(hvbf[(long)s2 * kH + c]);
            float a3 = bf2f(hvbf[(long)s3 * kH + c]);
            acc += (a0 + a1) + (a2 + a3);
        }
    }
    for (; e < en; e++) {
        int s0 = perm[e];
        if (c < kH) acc += bf2f(hvbf[(long)s0 * kH + c]);
    }
    if (c < kH) {
        float v = (1.f + eps[l]) * bf2f(hvbf[(long)n * kH + c]) + acc;
        hv_in[(long)n * KP_H + c] = f2bf(v);
    } else {
        hv_in[(long)n * KP_H + c] = 0;
    }
    long gt = (long)n * 320 + c;
    if (gt < 2 * kH) stats[gt] = 0.f;
}

// ---------------- vt_in[g] = bf16(sum_{rows of g} hvbf + vn[g]) (contiguous rows; batch sorted) ----------------
__global__ void vt_fin_k(const u16* __restrict__ hvbf, const float* __restrict__ vn,
                         const int* __restrict__ counts, const int* __restrict__ starts,
                         u16* __restrict__ vt_in) {
    int g = blockIdx.x, c = threadIdx.x;  // 320
    if (c >= kH) { vt_in[(long)g * KP_H + c] = 0; return; }
    int cnt = counts[g], st = starts[g];
    float acc = vn[g * kH + c];
    for (int i = 0; i < cnt; i++) acc += bf2f(hvbf[(long)(st + i) * kH + c]);
    vt_in[(long)g * KP_H + c] = f2bf(acc);
}

// ---------------- GEMM: C[M x store] = act(A[M x KP] @ Wt^T + bias); BK=64 ----------------
template<int ACT, int OUT_BF16, int BN_STATS>
__global__ __launch_bounds__(256) void gemm_k(
    const u16* __restrict__ A, const u16* __restrict__ Wt,
    const float* __restrict__ bias, void* __restrict__ out,
    float* __restrict__ stats,
    int KP, int NN, int out_stride, int store_cols) {
    __shared__ __align__(16) u16 lA[128][72];
    __shared__ __align__(16) u16 lB[64][72];
    __shared__ float sred[64][2];

    const int tid = threadIdx.x;
    const int lane = tid & 63;
    const int wave = tid >> 6;
    const int l16 = lane & 15;
    const int quad = lane >> 4;
    const int wm = (wave & 1) * 64;
    const int wn = (wave >> 1) * 32;
    const long tm = (long)blockIdx.x * 128;
    const int tn = blockIdx.y * 64;

    const int trow = tid >> 3;        // 0..31
    const int tcol = (tid & 7) * 8;   // 0..56 (u16 units)

    f32x4_t acc[4][2];
    #pragma unroll
    for (int i = 0; i < 4; i++)
        #pragma unroll
        for (int j = 0; j < 2; j++) acc[i][j] = (f32x4_t){0.f, 0.f, 0.f, 0.f};

    for (int k0 = 0; k0 < KP; k0 += 64) {
        __syncthreads();
        #pragma unroll
        for (int p = 0; p < 4; p++)
            *(uint4*)&lA[trow + 32 * p][tcol] =
                *(const uint4*)(A + (tm + trow + 32 * p) * KP + k0 + tcol);
        #pragma unroll
        for (int p = 0; p < 2; p++)
            *(uint4*)&lB[trow + 32 * p][tcol] =
                *(const uint4*)(Wt + (long)(tn + trow + 32 * p) * KP + k0 + tcol);
        __syncthreads();
        #pragma unroll
        for (int ks = 0; ks < 2; ks++) {
            bf16x8_t af[4], bfr[2];
            #pragma unroll
            for (int mt = 0; mt < 4; mt++)
                af[mt] = *(const bf16x8_t*)&lA[wm + mt * 16 + l16][ks * 32 + quad * 8];
            #pragma unroll
            for (int nt = 0; nt < 2; nt++)
                bfr[nt] = *(const bf16x8_t*)&lB[wn + nt * 16 + l16][ks * 32 + quad * 8];
            #pragma unroll
            for (int mt = 0; mt < 4; mt++)
                #pragma unroll
                for (int nt = 0; nt < 2; nt++)
                    acc[mt][nt] = __builtin_amdgcn_mfma_f32_16x16x32_bf16(af[mt], bfr[nt], acc[mt][nt], 0, 0, 0);
        }
    }

    if (BN_STATS) {
        if (tid < 64) { sred[tid][0] = 0.f; sred[tid][1] = 0.f; }
    }
    __syncthreads();

    #pragma unroll
    for (int nt = 0; nt < 2; nt++) {
        int col = tn + wn + nt * 16 + l16;
        float bv = (col < NN) ? bias[col] : 0.f;
        float s = 0.f, s2 = 0.f;
        #pragma unroll
        for (int mt = 0; mt < 4; mt++) {
            #pragma unroll
            for (int r = 0; r < 4; r++) {
                long row = tm + wm + mt * 16 + quad * 4 + r;
                float v = acc[mt][nt][r] + bv;
                if (ACT) v = fmaxf(v, 0.f);
                float sv = (col < NN) ? v : 0.f;
                if (col < store_cols) {
                    if (OUT_BF16) ((u16*)out)[row * out_stride + col] = f2bf(sv);
                    else          ((float*)out)[row * out_stride + col] = sv;
                }
                s += sv; s2 += sv * sv;
            }
        }
        if (BN_STATS) {
            atomicAdd(&sred[wn + nt * 16 + l16][0], s);
            atomicAdd(&sred[wn + nt * 16 + l16][1], s2);
        }
    }
    if (BN_STATS) {
        __syncthreads();
        if (tid < 64) {
            int col = tn + tid;
            if (col < NN) {
                atomicAdd(&stats[col], sred[tid][0]);
                atomicAdd(&stats[NN + col], sred[tid][1]);
            }
        }
    }
}

// ---------------- BN-apply + (relu) + residual; optionally writes hvbf = bf16(h_new + vn_next) ----------------
template<int RELU, int WRITE_HV>
__global__ void resid_k(float* __restrict__ h, u16* __restrict__ hvbf,
                        const u16* __restrict__ z, const float* __restrict__ stats,
                        const float* __restrict__ scale, const float* __restrict__ bias, int l,
                        const int* __restrict__ batch, const float* __restrict__ vn) {
    int n = blockIdx.x, c = threadIdx.x;
    if (c >= kH) return;
    float mean = stats[c] * (1.f / (float)kN);
    float var = stats[kH + c] * (1.f / (float)kN) - mean * mean;
    var = fmaxf(var, 0.f);
    float a = scale[l * kH + c] * rsqrtf(var + 1e-5f);
    float b = bias[l * kH + c] - mean * a;
    float v = bf2f(z[(long)n * KP_H + c]) * a + b;
    if (RELU) v = fmaxf(v, 0.f);
    float hn = h[(long)n * kH + c] + v;
    h[(long)n * kH + c] = hn;
    if (WRITE_HV) hvbf[(long)n * kH + c] = f2bf(hn + vn[batch[n] * kH + c]);
}

__global__ void vnupd_k(float* __restrict__ vn, const float* __restrict__ z) {
    int g = blockIdx.x, c = threadIdx.x;
    if (c < kH) vn[g * kH + c] += fmaxf(z[g * kH + c], 0.f);
}

// ---------------- h_rep cols [0,300): pooled mean of h (contiguous rows) ----------------
__global__ void pooled_k(const float* __restrict__ h, const int* __restrict__ counts,
                         const int* __restrict__ starts, u16* __restrict__ hrep) {
    int g = blockIdx.x, c = threadIdx.x;
    if (c >= kH) return;
    int cnt = counts[g], st = starts[g];
    float acc = 0.f;
    for (int i = 0; i < cnt; i++) acc += h[(long)(st + i) * kH + c];
    acc /= (float)(cnt > 0 ? cnt : 1);
    hrep[(long)g * KP_DG + c] = f2bf(acc);
}

// ---------------- h_rep cols [300,1536): id_pool | morgan | maccs | zero-pad ----------------
__global__ void hrep_rest_k(const float* __restrict__ morgan, const float* __restrict__ maccs,
                            const int* __restrict__ counts, u16* __restrict__ hrep) {
    long idx = (long)blockIdx.x * 256 + threadIdx.x;
    if (idx >= (long)kG * (KP_DG - kH)) return;
    int g = (int)(idx / (KP_DG - kH));
    int j = (int)(idx % (KP_DG - kH));
    int col = kH + j;
    u16 v;
    if (j < kF) {
        int c = counts[g];
        int q = (j < c) ? ((c - 1 - j) / kF + 1) : 0;  // #k in [0,c) with k%32==j
        v = f2bf((float)q / (float)(c > 0 ? c : 1));
    } else if (j < kF + 1024) {
        v = f2bf(morgan[(long)g * 1024 + (j - kF)]);
    } else if (j < kF + 1024 + 167) {
        v = f2bf(maccs[(long)g * 167 + (j - kF - 1024)]);
    } else {
        v = 0;
    }
    hrep[(long)g * KP_DG + col] = v;
}

// ---------------- final: out[g] = zp[g,:600] . Wp2 + bp2 ----------------
__global__ void final_k(const u16* __restrict__ zp, const float* __restrict__ Wp2,
                        const float* __restrict__ bp2, float* __restrict__ out) {
    int wave = threadIdx.x >> 6, lane = threadIdx.x & 63;
    int g = blockIdx.x * 4 + wave;
    float acc = 0.f;
    for (int c = lane; c < kH2; c += 64) acc += bf2f(zp[(long)g * KP_H2 + c]) * Wp2[c];
    #pragma unroll
    for (int off = 32; off; off >>= 1) acc += __shfl_down(acc, off);
    if (lane == 0) out[g] = acc + bp2[0];
}

extern "C" void kernel_launch(void* const* d_in, const int* in_sizes, int n_in,
                              void* d_out, int out_size, void* d_ws, size_t ws_size,
                              hipStream_t stream) {
    const float* x      = (const float*)d_in[0];
    const float* morgan = (const float*)d_in[1];
    const float* maccs  = (const float*)d_in[2];
    const int*   ei     = (const int*)d_in[3];
    const int*   batch  = (const int*)d_in[4];
    const float* W_emb  = (const float*)d_in[5];
    const float* b_emb  = (const float*)d_in[6];
    const float* gin_W1 = (const float*)d_in[7];
    const float* gin_b1 = (const float*)d_in[8];
    const float* gin_W2 = (const float*)d_in[9];
    const float* gin_b2 = (const float*)d_in[10];
    const float* bn_scale = (const float*)d_in[11];
    const float* bn_bias  = (const float*)d_in[12];
    const float* eps    = (const float*)d_in[13];
    const float* vn0    = (const float*)d_in[14];
    const float* vn_W1  = (const float*)d_in[15];
    const float* vn_b1  = (const float*)d_in[16];
    const float* vn_W2  = (const float*)d_in[17];
    const float* vn_b2  = (const float*)d_in[18];
    const float* Wp1    = (const float*)d_in[19];
    const float* bp1    = (const float*)d_in[20];
    const float* Wp2    = (const float*)d_in[21];
    const float* bp2    = (const float*)d_in[22];
    float* out = (float*)d_out;

    char* ws = (char*)d_ws;
    size_t off = 0;
    auto alloc = [&](size_t bytes) -> char* {
        char* p = ws + off;
        off += (bytes + 255) & ~(size_t)255;
        return p;
    };
    float* h    = (float*)alloc((size_t)kN * kH * 4);       // 78.6 MB
    u16*   hvbf = (u16*)alloc((size_t)kN * kH * 2);         // 39.3 MB bf16(h+vn[batch])
    u16*   hv   = (u16*)alloc((size_t)kN * KP_H * 2);       // 41.9 MB (hv_in, then z2 bf16)
    char*  S    = alloc((size_t)C_ROWS * KP_H2 * 2);        // 21.0 MB scratch region
    float* vn   = (float*)alloc((size_t)kG * kH * 4);       // 2.5 MB
    int* counts = (int*)alloc(kG * 4);
    int* starts = (int*)alloc(kG * 4);
    float* stats = (float*)alloc(2 * kH * 4);
    int* cnt_n  = (int*)alloc((size_t)kN * 4);
    int* start_n = (int*)alloc((size_t)(kN + 1) * 4);
    int* fill_n = (int*)alloc((size_t)kN * 4);
    int* bsum   = (int*)alloc((kN / 1024) * 4);
    int* perm   = (int*)alloc((size_t)kE * 4);
    u16* Wt_g1 = (u16*)alloc((size_t)kL * NP_H2 * KP_H * 2);
    u16* Wt_g2 = (u16*)alloc((size_t)kL * NP_H * KP_H2 * 2);
    u16* Wt_v1 = (u16*)alloc((size_t)(kL - 1) * NP_H2 * KP_H * 2);
    u16* Wt_v2 = (u16*)alloc((size_t)(kL - 1) * NP_H * KP_H2 * 2);
    u16* Wt_p1 = (u16*)alloc((size_t)NP_H2 * KP_DG * 2);
    if (off > ws_size) return;  // ~197 MB required

    // scratch-region overlays (disjoint lifetimes vs z1c chunk buffer):
    u16*   z1c   = (u16*)S;                                        // [16384, 640] bf16 (node chunks)
    u16*   vt_in = (u16*)S;                                        // [2048, 320] bf16
    u16*   z1v   = (u16*)(S + (size_t)kG * KP_H * 2);              // [2048, 640] bf16
    float* z2v   = (float*)(S + (size_t)kG * (KP_H + KP_H2) * 2);  // [2048, 300] f32
    u16*   hrep  = (u16*)S;                                        // [2048, 1536] bf16 (post-layers)
    u16*   zp    = (u16*)(S + (size_t)kG * KP_DG * 2);             // [2048, 640] bf16

    // weight transposes (f32 -> padded bf16)
    {
        long t1 = (long)kL * NP_H2 * KP_H;
        transpose_k<<<dim3((unsigned)((t1 + 255) / 256)), 256, 0, stream>>>(gin_W1, Wt_g1, kH, kH2, NP_H2, KP_H, t1);
        long t2 = (long)kL * NP_H * KP_H2;
        transpose_k<<<dim3((unsigned)((t2 + 255) / 256)), 256, 0, stream>>>(gin_W2, Wt_g2, kH2, kH, NP_H, KP_H2, t2);
        long t3 = (long)(kL - 1) * NP_H2 * KP_H;
        transpose_k<<<dim3((unsigned)((t3 + 255) / 256)), 256, 0, stream>>>(vn_W1, Wt_v1, kH, kH2, NP_H2, KP_H, t3);
        long t4 = (long)(kL - 1) * NP_H * KP_H2;
        transpose_k<<<dim3((unsigned)((t4 + 255) / 256)), 256, 0, stream>>>(vn_W2, Wt_v2, kH2, kH, NP_H, KP_H2, t4);
        long t5 = (long)NP_H2 * KP_DG;
        transpose_k<<<dim3((unsigned)((t5 + 255) / 256)), 256, 0, stream>>>(Wp1, Wt_p1, kDG, kH2, NP_H2, KP_DG, t5);
    }

    // graph ranges + node CSR
    hipMemsetAsync(counts, 0, kG * 4, stream);
    hipMemsetAsync(cnt_n, 0, (size_t)kN * 4, stream);
    hipMemsetAsync(fill_n, 0, (size_t)kN * 4, stream);
    hist_g_k<<<kN / 256, 256, 0, stream>>>(batch, counts);
    scan_g_k<<<1, 1024, 0, stream>>>(counts, starts);
    hist_n_k<<<kE / 256, 256, 0, stream>>>(ei, cnt_n);
    scanA_k<<<kN / 1024, 1024, 0, stream>>>(cnt_n, start_n, bsum);
    scanB_k<<<1, 64, 0, stream>>>(bsum);
    scanC_k<<<kN / 1024, 1024, 0, stream>>>(start_n, bsum);
    fill_n_k<<<kE / 256, 256, 0, stream>>>(ei, start_n, fill_n, perm);

    embed_k<<<kN, 320, 0, stream>>>(x, W_emb, b_emb, h);
    vninit_k<<<kG, 320, 0, stream>>>(vn0, vn);
    hv0_k<<<kN, 320, 0, stream>>>(h, vn0, hvbf);

    for (int l = 0; l < kL; l++) {
        gather_combine_k<<<kN, 320, 0, stream>>>(hvbf, start_n, perm, eps, l, hv, stats);
        if (l < kL - 1) {
            vt_fin_k<<<kG, 320, 0, stream>>>(hvbf, vn, counts, starts, vt_in);
            gemm_k<1, 1, 0><<<dim3(16, 10), 256, 0, stream>>>(
                vt_in, Wt_v1 + (size_t)l * NP_H2 * KP_H, vn_b1 + l * kH2,
                z1v, nullptr, KP_H, kH2, KP_H2, KP_H2);
            gemm_k<0, 0, 0><<<dim3(16, 5), 256, 0, stream>>>(
                z1v, Wt_v2 + (size_t)l * NP_H * KP_H2, vn_b2 + l * kH,
                z2v, nullptr, KP_H2, kH, kH, kH);
            vnupd_k<<<kG, 320, 0, stream>>>(vn, z2v);  // vn becomes vn_{l+1}
        }
        // node MLP in M-chunks; z2 (bf16) overwrites hv rows in place
        for (int c = 0; c < C_CHUNK; c++) {
            const u16* Ain = hv + (size_t)c * C_ROWS * KP_H;
            gemm_k<1, 1, 0><<<dim3(C_ROWS / 128, 10), 256, 0, stream>>>(
                Ain, Wt_g1 + (size_t)l * NP_H2 * KP_H, gin_b1 + l * kH2,
                z1c, nullptr, KP_H, kH2, KP_H2, KP_H2);
            gemm_k<0, 1, 1><<<dim3(C_ROWS / 128, 5), 256, 0, stream>>>(
                z1c, Wt_g2 + (size_t)l * NP_H * KP_H2, gin_b2 + l * kH,
                (void*)(hv + (size_t)c * C_ROWS * KP_H), stats, KP_H2, kH, KP_H, kH);
        }
        if (l < kL - 1)
            resid_k<1, 1><<<kN, 320, 0, stream>>>(h, hvbf, hv, stats, bn_scale, bn_bias, l, batch, vn);
        else
            resid_k<0, 0><<<kN, 320, 0, stream>>>(h, hvbf, hv, stats, bn_scale, bn_bias, l, batch, vn);
    }

    pooled_k<<<kG, 320, 0, stream>>>(h, counts, starts, hrep);
    {
        long tr = (long)kG * (KP_DG - kH);
        hrep_rest_k<<<dim3((unsigned)((tr + 255) / 256)), 256, 0, stream>>>(morgan, maccs, counts, hrep);
    }
    gemm_k<1, 1, 0><<<dim3(16, 10), 256, 0, stream>>>(
        hrep, Wt_p1, bp1, zp, nullptr, KP_DG, kH2, KP_H2, KP_H2);
    final_k<<<kG / 4, 256, 0, stream>>>(zp, Wp2, bp2, out);
}

// Round 6
// 1786.420 us; speedup vs baseline: 1.5217x; 1.1356x over previous
//
#include <hip/hip_runtime.h>

typedef unsigned short u16;
typedef unsigned int u32;
typedef __attribute__((ext_vector_type(8))) short bf16x8_t;
typedef __attribute__((ext_vector_type(4))) float f32x4_t;

// problem constants
#define kN 65536
#define kE 262144
#define kG 2048
#define kH 300
#define kH2 600
#define kL 5
#define kF 32
#define kDG 1523
// padded dims
#define KP_H 320     // K pad of H (mult of 64)
#define KP_H2 640    // K pad of 2H
#define KP_DG 1536   // K pad of DG
#define NP_H2 640    // N pad of 2H (mult of 128)
#define NP_H 384     // N pad of H (mult of 128)
// M-chunking for node MLP
#define C_CHUNK 4
#define C_ROWS (kN / C_CHUNK)   // 16384
// hvbf row stride (u16 / u32)
#define HVS 320
#define HVS32 160

__device__ __forceinline__ float bf2f(u16 x) {
    union { u32 u; float f; } v; v.u = ((u32)x) << 16; return v.f;
}
__device__ __forceinline__ u16 f2bf(float f) {
    union { float f; u32 u; } v; v.f = f;
    u32 u = v.u;
    u32 r = (u + 0x7fffu + ((u >> 16) & 1u)) >> 16;  // RNE
    return (u16)r;
}
__device__ __forceinline__ float blo(u32 v) { return bf2f((u16)(v & 0xffffu)); }
__device__ __forceinline__ float bhi(u32 v) { return bf2f((u16)(v >> 16)); }
__device__ __forceinline__ u32 pack2(float lo, float hi) {
    return (u32)f2bf(lo) | ((u32)f2bf(hi) << 16);
}

// async 16B global -> LDS (wave-uniform lds base; lane writes base + lane*16)
__device__ __forceinline__ void gld16(const u16* g, u16* l) {
    __builtin_amdgcn_global_load_lds(
        (const __attribute__((address_space(1))) u32*)g,
        (__attribute__((address_space(3))) u32*)l, 16, 0, 0);
}

// ---------------- weight transpose: W[b][k][n] (f32) -> Wt[b][n][k] (bf16), zero-padded ----------------
__global__ void transpose_k(const float* __restrict__ W, u16* __restrict__ Wt,
                            int K, int NN, int NP, int KP, long total) {
    long idx = (long)blockIdx.x * 256 + threadIdx.x;
    if (idx >= total) return;
    int per = NP * KP;
    int b = (int)(idx / per);
    int r = (int)(idx % per);
    int n = r / KP;
    int k = r % KP;
    u16 v = 0;
    if (n < NN && k < K) v = f2bf(W[(long)b * K * NN + (long)k * NN + n]);
    Wt[idx] = v;
}

// ---------------- graph histogram + scan (G=2048) ----------------
__global__ void hist_g_k(const int* __restrict__ batch, int* __restrict__ counts) {
    int n = blockIdx.x * 256 + threadIdx.x;
    if (n < kN) atomicAdd(&counts[batch[n]], 1);
}

__global__ void scan_g_k(const int* __restrict__ counts, int* __restrict__ starts) {
    __shared__ int s[1024];
    int t = threadIdx.x;
    int c0 = counts[2 * t], c1 = counts[2 * t + 1];
    s[t] = c0 + c1;
    __syncthreads();
    for (int off = 1; off < 1024; off <<= 1) {
        int v = (t >= off) ? s[t - off] : 0;
        __syncthreads();
        s[t] += v;
        __syncthreads();
    }
    int excl = (t > 0) ? s[t - 1] : 0;
    starts[2 * t] = excl;
    starts[2 * t + 1] = excl + c0;
}

// ---------------- node CSR build (dst-sorted edges), 3-phase scan ----------------
__global__ void hist_n_k(const int* __restrict__ ei, int* __restrict__ cnt) {
    int e = blockIdx.x * 256 + threadIdx.x;
    if (e < kE) atomicAdd(&cnt[ei[kE + e]], 1);  // dst
}

__global__ void scanA_k(const int* __restrict__ cnt, int* __restrict__ start, int* __restrict__ bsum) {
    __shared__ int s[1024];
    int b = blockIdx.x, t = threadIdx.x;
    int v = cnt[b * 1024 + t];
    s[t] = v;
    __syncthreads();
    for (int off = 1; off < 1024; off <<= 1) {
        int u = (t >= off) ? s[t - off] : 0;
        __syncthreads();
        s[t] += u;
        __syncthreads();
    }
    start[b * 1024 + t] = s[t] - v;  // block-local exclusive
    if (t == 1023) bsum[b] = s[1023];
}

__global__ void scanB_k(int* __restrict__ bsum) {
    if (threadIdx.x == 0) {
        int s = 0;
        for (int i = 0; i < kN / 1024; i++) { s += bsum[i]; bsum[i] = s; }  // inclusive
    }
}

__global__ void scanC_k(int* __restrict__ start, const int* __restrict__ bsum) {
    int b = blockIdx.x, t = threadIdx.x;
    int add = (b > 0) ? bsum[b - 1] : 0;
    start[b * 1024 + t] += add;
    if (b == kN / 1024 - 1 && t == 1023) start[kN] = bsum[kN / 1024 - 1];
}

__global__ void fill_n_k(const int* __restrict__ ei, const int* __restrict__ start,
                         int* __restrict__ fill, int* __restrict__ perm) {
    int e = blockIdx.x * 256 + threadIdx.x;
    if (e >= kE) return;
    int s = ei[e], d = ei[kE + e];
    int pos = start[d] + atomicAdd(&fill[d], 1);
    perm[pos] = s;
}

// ---------------- node embedding: h = x @ W_emb + b_emb ----------------
__global__ void embed_k(const float* __restrict__ x, const float* __restrict__ W,
                        const float* __restrict__ b, float* __restrict__ h) {
    int n = blockIdx.x, j = threadIdx.x;
    if (j >= kH) return;
    float acc = b[j];
    #pragma unroll
    for (int d = 0; d < 9; d++) acc += x[n * 9 + d] * W[d * kH + j];
    h[(long)n * kH + j] = acc;
}

__global__ void vninit_k(const float* __restrict__ vn0, float* __restrict__ vn) {
    int g = blockIdx.x, c = threadIdx.x;
    if (c < kH) vn[g * kH + c] = vn0[c];
}

// hvbf[n] = bf16(h[n] + vn0[c])  (layer-0 init; vn identical across graphs)
__global__ void hv0_k(const float* __restrict__ h, const float* __restrict__ vn0,
                      u16* __restrict__ hvbf) {
    int n = blockIdx.x, c = threadIdx.x;
    if (c < kH) hvbf[(long)n * HVS + c] = f2bf(h[(long)n * kH + c] + vn0[c]);
}

// ---------------- gather + combine: one WAVE per node, u32 (2-col) lanes ----------------
// hv_in[n] = bf16((1+eps)*hvbf[n] + sum_e hvbf[src_e]); zero K-pad; zero stats
__global__ __launch_bounds__(256) void gather_combine_k(
    const u32* __restrict__ hv32, const int* __restrict__ start_n,
    const int* __restrict__ perm, const float* __restrict__ eps, int l,
    u32* __restrict__ out32, float* __restrict__ stats) {
    int tid = threadIdx.x;
    int wave = tid >> 6, lane = tid & 63;
    int n = blockIdx.x * 4 + wave;
    int st = start_n[n], en = start_n[n + 1];
    int i0 = lane, i1 = lane + 64, i2 = lane + 128;
    bool p2 = (i2 < HVS32 - 10);  // i2 < 150 (cols < 300)
    float a0 = 0.f, b0 = 0.f, a1 = 0.f, b1 = 0.f, a2 = 0.f, b2 = 0.f;
    int e = st;
    for (; e + 2 <= en; e += 2) {
        const u32* rA = hv32 + (long)perm[e] * HVS32;
        const u32* rB = hv32 + (long)perm[e + 1] * HVS32;
        u32 vA0 = rA[i0], vA1 = rA[i1], vA2 = p2 ? rA[i2] : 0u;
        u32 vB0 = rB[i0], vB1 = rB[i1], vB2 = p2 ? rB[i2] : 0u;
        a0 += blo(vA0) + blo(vB0); b0 += bhi(vA0) + bhi(vB0);
        a1 += blo(vA1) + blo(vB1); b1 += bhi(vA1) + bhi(vB1);
        a2 += blo(vA2) + blo(vB2); b2 += bhi(vA2) + bhi(vB2);
    }
    if (e < en) {
        const u32* rA = hv32 + (long)perm[e] * HVS32;
        u32 vA0 = rA[i0], vA1 = rA[i1], vA2 = p2 ? rA[i2] : 0u;
        a0 += blo(vA0); b0 += bhi(vA0);
        a1 += blo(vA1); b1 += bhi(vA1);
        a2 += blo(vA2); b2 += bhi(vA2);
    }
    const u32* self = hv32 + (long)n * HVS32;
    float ep = 1.f + eps[l];
    u32 s0 = self[i0], s1 = self[i1];
    u32* o = out32 + (long)n * HVS32;
    o[i0] = pack2(ep * blo(s0) + a0, ep * bhi(s0) + b0);
    o[i1] = pack2(ep * blo(s1) + a1, ep * bhi(s1) + b1);
    if (p2) {
        u32 s2 = self[i2];
        o[i2] = pack2(ep * blo(s2) + a2, ep * bhi(s2) + b2);
    } else if (i2 < HVS32) {
        o[i2] = 0u;  // K-pad cols 300..319
    }
    int gz = blockIdx.x * 256 + tid;
    if (gz < 2 * kH) stats[gz] = 0.f;
}

// ---------------- vt_in[g] = bf16(sum_{rows of g} hvbf + vn[g]) (contiguous rows) ----------------
__global__ void vt_fin_k(const u16* __restrict__ hvbf, const float* __restrict__ vn,
                         const int* __restrict__ counts, const int* __restrict__ starts,
                         u16* __restrict__ vt_in) {
    int g = blockIdx.x, c = threadIdx.x;  // 320
    if (c >= kH) { vt_in[(long)g * KP_H + c] = 0; return; }
    int cnt = counts[g], st = starts[g];
    float acc = vn[g * kH + c];
    for (int i = 0; i < cnt; i++) acc += bf2f(hvbf[(long)(st + i) * HVS + c]);
    vt_in[(long)g * KP_H + c] = f2bf(acc);
}

// ---------------- GEMM: 128x128 tile, BK=64, global_load_lds + XOR-swizzled LDS ----------------
// A: bf16 [M][KP] (zero K-pad). Wt: bf16 [NP][KP] rows (zero-padded). M%128==0, grid.y*128<=NP.
template<int ACT, int OUT_BF16, int BN_STATS>
__global__ __launch_bounds__(256) void gemm_k(
    const u16* __restrict__ A, const u16* __restrict__ Wt,
    const float* __restrict__ bias, void* __restrict__ out,
    float* __restrict__ stats,
    int KP, int NN, int out_stride, int store_cols) {
    __shared__ __align__(16) u16 lA[128 * 64];
    __shared__ __align__(16) u16 lB[128 * 64];
    __shared__ float sred[128][2];

    const int tid = threadIdx.x;
    const int lane = tid & 63;
    const int wave = tid >> 6;
    const int l16 = lane & 15;
    const int quad = lane >> 4;
    const int wm = (wave & 1) * 64;
    const int wn = (wave >> 1) * 64;
    const long tm = (long)blockIdx.x * 128;
    const int tn = blockIdx.y * 128;

    const int srow = lane >> 3;            // 0..7
    const int sch = (lane & 7) ^ srow;     // XOR-swizzled logical k-chunk

    f32x4_t acc[4][4];
    #pragma unroll
    for (int i = 0; i < 4; i++)
        #pragma unroll
        for (int j = 0; j < 4; j++) acc[i][j] = (f32x4_t){0.f, 0.f, 0.f, 0.f};

    for (int k0 = 0; k0 < KP; k0 += 64) {
        __syncthreads();
        #pragma unroll
        for (int j = 0; j < 4; j++) {
            int rb = wave * 32 + j * 8;          // wave-uniform base row
            int r = rb + srow;                   // r & 7 == srow
            gld16(A + (tm + r) * KP + k0 + sch * 8, &lA[rb * 64]);
            gld16(Wt + (long)(tn + r) * KP + k0 + sch * 8, &lB[rb * 64]);
        }
        __syncthreads();
        #pragma unroll
        for (int ks = 0; ks < 2; ks++) {
            bf16x8_t af[4], bfr[4];
            #pragma unroll
            for (int mt = 0; mt < 4; mt++) {
                int row = wm + mt * 16 + l16;
                int phys = (ks * 4 + quad) ^ (l16 & 7);
                af[mt] = *(const bf16x8_t*)&lA[row * 64 + phys * 8];
            }
            #pragma unroll
            for (int nt = 0; nt < 4; nt++) {
                int row = wn + nt * 16 + l16;
                int phys = (ks * 4 + quad) ^ (l16 & 7);
                bfr[nt] = *(const bf16x8_t*)&lB[row * 64 + phys * 8];
            }
            #pragma unroll
            for (int mt = 0; mt < 4; mt++)
                #pragma unroll
                for (int nt = 0; nt < 4; nt++)
                    acc[mt][nt] = __builtin_amdgcn_mfma_f32_16x16x32_bf16(af[mt], bfr[nt], acc[mt][nt], 0, 0, 0);
        }
    }

    if (BN_STATS) {
        if (tid < 128) { sred[tid][0] = 0.f; sred[tid][1] = 0.f; }
    }
    __syncthreads();

    #pragma unroll
    for (int nt = 0; nt < 4; nt++) {
        int col = tn + wn + nt * 16 + l16;
        float bv = (col < NN) ? bias[col] : 0.f;
        float s = 0.f, s2 = 0.f;
        #pragma unroll
        for (int mt = 0; mt < 4; mt++) {
            #pragma unroll
            for (int r = 0; r < 4; r++) {
                long row = tm + wm + mt * 16 + quad * 4 + r;
                float v = acc[mt][nt][r] + bv;
                if (ACT) v = fmaxf(v, 0.f);
                float sv = (col < NN) ? v : 0.f;
                if (col < store_cols) {
                    if (OUT_BF16) ((u16*)out)[row * out_stride + col] = f2bf(sv);
                    else          ((float*)out)[row * out_stride + col] = sv;
                }
                s += sv; s2 += sv * sv;
            }
        }
        if (BN_STATS) {
            atomicAdd(&sred[wn + nt * 16 + l16][0], s);
            atomicAdd(&sred[wn + nt * 16 + l16][1], s2);
        }
    }
    if (BN_STATS) {
        __syncthreads();
        if (tid < 128) {
            int col = tn + tid;
            if (col < NN) {
                atomicAdd(&stats[col], sred[tid][0]);
                atomicAdd(&stats[NN + col], sred[tid][1]);
            }
        }
    }
}

// ---------------- BN-apply + (relu) + residual; optionally writes hvbf = bf16(h_new + vn_next) ----------------
template<int RELU, int WRITE_HV>
__global__ void resid_k(float* __restrict__ h, u16* __restrict__ hvbf,
                        const u16* __restrict__ z, const float* __restrict__ stats,
                        const float* __restrict__ scale, const float* __restrict__ bias, int l,
                        const int* __restrict__ batch, const float* __restrict__ vn) {
    int n = blockIdx.x, c = threadIdx.x;
    if (c >= kH) return;
    float mean = stats[c] * (1.f / (float)kN);
    float var = stats[kH + c] * (1.f / (float)kN) - mean * mean;
    var = fmaxf(var, 0.f);
    float a = scale[l * kH + c] * rsqrtf(var + 1e-5f);
    float b = bias[l * kH + c] - mean * a;
    float v = bf2f(z[(long)n * KP_H + c]) * a + b;
    if (RELU) v = fmaxf(v, 0.f);
    float hn = h[(long)n * kH + c] + v;
    h[(long)n * kH + c] = hn;
    if (WRITE_HV) hvbf[(long)n * HVS + c] = f2bf(hn + vn[batch[n] * kH + c]);
}

__global__ void vnupd_k(float* __restrict__ vn, const float* __restrict__ z) {
    int g = blockIdx.x, c = threadIdx.x;
    if (c < kH) vn[g * kH + c] += fmaxf(z[g * kH + c], 0.f);
}

// ---------------- h_rep cols [0,300): pooled mean of h (contiguous rows) ----------------
__global__ void pooled_k(const float* __restrict__ h, const int* __restrict__ counts,
                         const int* __restrict__ starts, u16* __restrict__ hrep) {
    int g = blockIdx.x, c = threadIdx.x;
    if (c >= kH) return;
    int cnt = counts[g], st = starts[g];
    float acc = 0.f;
    for (int i = 0; i < cnt; i++) acc += h[(long)(st + i) * kH + c];
    acc /= (float)(cnt > 0 ? cnt : 1);
    hrep[(long)g * KP_DG + c] = f2bf(acc);
}

// ---------------- h_rep cols [300,1536): id_pool | morgan | maccs | zero-pad ----------------
__global__ void hrep_rest_k(const float* __restrict__ morgan, const float* __restrict__ maccs,
                            const int* __restrict__ counts, u16* __restrict__ hrep) {
    long idx = (long)blockIdx.x * 256 + threadIdx.x;
    if (idx >= (long)kG * (KP_DG - kH)) return;
    int g = (int)(idx / (KP_DG - kH));
    int j = (int)(idx % (KP_DG - kH));
    int col = kH + j;
    u16 v;
    if (j < kF) {
        int c = counts[g];
        int q = (j < c) ? ((c - 1 - j) / kF + 1) : 0;  // #k in [0,c) with k%32==j
        v = f2bf((float)q / (float)(c > 0 ? c : 1));
    } else if (j < kF + 1024) {
        v = f2bf(morgan[(long)g * 1024 + (j - kF)]);
    } else if (j < kF + 1024 + 167) {
        v = f2bf(maccs[(long)g * 167 + (j - kF - 1024)]);
    } else {
        v = 0;
    }
    hrep[(long)g * KP_DG + col] = v;
}

// ---------------- final: out[g] = zp[g,:600] . Wp2 + bp2 ----------------
__global__ void final_k(const u16* __restrict__ zp, const float* __restrict__ Wp2,
                        const float* __restrict__ bp2, float* __restrict__ out) {
    int wave = threadIdx.x >> 6, lane = threadIdx.x & 63;
    int g = blockIdx.x * 4 + wave;
    float acc = 0.f;
    for (int c = lane; c < kH2; c += 64) acc += bf2f(zp[(long)g * KP_H2 + c]) * Wp2[c];
    #pragma unroll
    for (int off = 32; off; off >>= 1) acc += __shfl_down(acc, off);
    if (lane == 0) out[g] = acc + bp2[0];
}

extern "C" void kernel_launch(void* const* d_in, const int* in_sizes, int n_in,
                              void* d_out, int out_size, void* d_ws, size_t ws_size,
                              hipStream_t stream) {
    const float* x      = (const float*)d_in[0];
    const float* morgan = (const float*)d_in[1];
    const float* maccs  = (const float*)d_in[2];
    const int*   ei     = (const int*)d_in[3];
    const int*   batch  = (const int*)d_in[4];
    const float* W_emb  = (const float*)d_in[5];
    const float* b_emb  = (const float*)d_in[6];
    const float* gin_W1 = (const float*)d_in[7];
    const float* gin_b1 = (const float*)d_in[8];
    const float* gin_W2 = (const float*)d_in[9];
    const float* gin_b2 = (const float*)d_in[10];
    const float* bn_scale = (const float*)d_in[11];
    const float* bn_bias  = (const float*)d_in[12];
    const float* eps    = (const float*)d_in[13];
    const float* vn0    = (const float*)d_in[14];
    const float* vn_W1  = (const float*)d_in[15];
    const float* vn_b1  = (const float*)d_in[16];
    const float* vn_W2  = (const float*)d_in[17];
    const float* vn_b2  = (const float*)d_in[18];
    const float* Wp1    = (const float*)d_in[19];
    const float* bp1    = (const float*)d_in[20];
    const float* Wp2    = (const float*)d_in[21];
    const float* bp2    = (const float*)d_in[22];
    float* out = (float*)d_out;

    char* ws = (char*)d_ws;
    size_t off = 0;
    auto alloc = [&](size_t bytes) -> char* {
        char* p = ws + off;
        off += (bytes + 255) & ~(size_t)255;
        return p;
    };
    float* h    = (float*)alloc((size_t)kN * kH * 4);       // 78.6 MB
    u16*   hvbf = (u16*)alloc((size_t)kN * HVS * 2);        // 41.9 MB bf16(h+vn[batch]), padded
    u16*   hv   = (u16*)alloc((size_t)kN * KP_H * 2);       // 41.9 MB (hv_in, then z2 bf16)
    char*  S    = alloc((size_t)C_ROWS * KP_H2 * 2);        // 21.0 MB scratch region
    float* vn   = (float*)alloc((size_t)kG * kH * 4);       // 2.5 MB
    int* counts = (int*)alloc(kG * 4);
    int* starts = (int*)alloc(kG * 4);
    float* stats = (float*)alloc(2 * kH * 4);
    int* cnt_n  = (int*)alloc((size_t)kN * 4);
    int* start_n = (int*)alloc((size_t)(kN + 1) * 4);
    int* fill_n = (int*)alloc((size_t)kN * 4);
    int* bsum   = (int*)alloc((kN / 1024) * 4);
    int* perm   = (int*)alloc((size_t)kE * 4);
    u16* Wt_g1 = (u16*)alloc((size_t)kL * NP_H2 * KP_H * 2);
    u16* Wt_g2 = (u16*)alloc((size_t)kL * NP_H * KP_H2 * 2);
    u16* Wt_v1 = (u16*)alloc((size_t)(kL - 1) * NP_H2 * KP_H * 2);
    u16* Wt_v2 = (u16*)alloc((size_t)(kL - 1) * NP_H * KP_H2 * 2);
    u16* Wt_p1 = (u16*)alloc((size_t)NP_H2 * KP_DG * 2);
    if (off > ws_size) return;  // ~200 MB required

    // scratch-region overlays (disjoint lifetimes vs z1c chunk buffer):
    u16*   z1c   = (u16*)S;                                        // [16384, 640] bf16 (node chunks)
    u16*   vt_in = (u16*)S;                                        // [2048, 320] bf16
    u16*   z1v   = (u16*)(S + (size_t)kG * KP_H * 2);              // [2048, 640] bf16
    float* z2v   = (float*)(S + (size_t)kG * (KP_H + KP_H2) * 2);  // [2048, 300] f32
    u16*   hrep  = (u16*)S;                                        // [2048, 1536] bf16 (post-layers)
    u16*   zp    = (u16*)(S + (size_t)kG * KP_DG * 2);             // [2048, 640] bf16

    // weight transposes (f32 -> padded bf16)
    {
        long t1 = (long)kL * NP_H2 * KP_H;
        transpose_k<<<dim3((unsigned)((t1 + 255) / 256)), 256, 0, stream>>>(gin_W1, Wt_g1, kH, kH2, NP_H2, KP_H, t1);
        long t2 = (long)kL * NP_H * KP_H2;
        transpose_k<<<dim3((unsigned)((t2 + 255) / 256)), 256, 0, stream>>>(gin_W2, Wt_g2, kH2, kH, NP_H, KP_H2, t2);
        long t3 = (long)(kL - 1) * NP_H2 * KP_H;
        transpose_k<<<dim3((unsigned)((t3 + 255) / 256)), 256, 0, stream>>>(vn_W1, Wt_v1, kH, kH2, NP_H2, KP_H, t3);
        long t4 = (long)(kL - 1) * NP_H * KP_H2;
        transpose_k<<<dim3((unsigned)((t4 + 255) / 256)), 256, 0, stream>>>(vn_W2, Wt_v2, kH2, kH, NP_H, KP_H2, t4);
        long t5 = (long)NP_H2 * KP_DG;
        transpose_k<<<dim3((unsigned)((t5 + 255) / 256)), 256, 0, stream>>>(Wp1, Wt_p1, kDG, kH2, NP_H2, KP_DG, t5);
    }

    // graph ranges + node CSR
    hipMemsetAsync(counts, 0, kG * 4, stream);
    hipMemsetAsync(cnt_n, 0, (size_t)kN * 4, stream);
    hipMemsetAsync(fill_n, 0, (size_t)kN * 4, stream);
    hist_g_k<<<kN / 256, 256, 0, stream>>>(batch, counts);
    scan_g_k<<<1, 1024, 0, stream>>>(counts, starts);
    hist_n_k<<<kE / 256, 256, 0, stream>>>(ei, cnt_n);
    scanA_k<<<kN / 1024, 1024, 0, stream>>>(cnt_n, start_n, bsum);
    scanB_k<<<1, 64, 0, stream>>>(bsum);
    scanC_k<<<kN / 1024, 1024, 0, stream>>>(start_n, bsum);
    fill_n_k<<<kE / 256, 256, 0, stream>>>(ei, start_n, fill_n, perm);

    embed_k<<<kN, 320, 0, stream>>>(x, W_emb, b_emb, h);
    vninit_k<<<kG, 320, 0, stream>>>(vn0, vn);
    hv0_k<<<kN, 320, 0, stream>>>(h, vn0, hvbf);

    for (int l = 0; l < kL; l++) {
        gather_combine_k<<<kN / 4, 256, 0, stream>>>(
            (const u32*)hvbf, start_n, perm, eps, l, (u32*)hv, stats);
        if (l < kL - 1) {
            vt_fin_k<<<kG, 320, 0, stream>>>(hvbf, vn, counts, starts, vt_in);
            gemm_k<1, 1, 0><<<dim3(16, NP_H2 / 128), 256, 0, stream>>>(
                vt_in, Wt_v1 + (size_t)l * NP_H2 * KP_H, vn_b1 + l * kH2,
                z1v, nullptr, KP_H, kH2, KP_H2, KP_H2);
            gemm_k<0, 0, 0><<<dim3(16, NP_H / 128), 256, 0, stream>>>(
                z1v, Wt_v2 + (size_t)l * NP_H * KP_H2, vn_b2 + l * kH,
                z2v, nullptr, KP_H2, kH, kH, kH);
            vnupd_k<<<kG, 320, 0, stream>>>(vn, z2v);  // vn becomes vn_{l+1}
        }
        // node MLP in M-chunks; z2 (bf16) overwrites hv rows in place
        for (int c = 0; c < C_CHUNK; c++) {
            const u16* Ain = hv + (size_t)c * C_ROWS * KP_H;
            gemm_k<1, 1, 0><<<dim3(C_ROWS / 128, NP_H2 / 128), 256, 0, stream>>>(
                Ain, Wt_g1 + (size_t)l * NP_H2 * KP_H, gin_b1 + l * kH2,
                z1c, nullptr, KP_H, kH2, KP_H2, KP_H2);
            gemm_k<0, 1, 1><<<dim3(C_ROWS / 128, NP_H / 128), 256, 0, stream>>>(
                z1c, Wt_g2 + (size_t)l * NP_H * KP_H2, gin_b2 + l * kH,
                (void*)(hv + (size_t)c * C_ROWS * KP_H), stats, KP_H2, kH, KP_H, KP_H);
        }
        if (l < kL - 1)
            resid_k<1, 1><<<kN, 320, 0, stream>>>(h, hvbf, hv, stats, bn_scale, bn_bias, l, batch, vn);
        else
            resid_k<0, 0><<<kN, 320, 0, stream>>>(h, hvbf, hv, stats, bn_scale, bn_bias, l, batch, vn);
    }

    pooled_k<<<kG, 320, 0, stream>>>(h, counts, starts, hrep);
    {
        long tr = (long)kG * (KP_DG - kH);
        hrep_rest_k<<<dim3((unsigned)((tr + 255) / 256)), 256, 0, stream>>>(morgan, maccs, counts, hrep);
    }
    gemm_k<1, 1, 0><<<dim3(16, NP_H2 / 128), 256, 0, stream>>>(
        hrep, Wt_p1, bp1, zp, nullptr, KP_DG, kH2, KP_H2, KP_H2);
    final_k<<<kG / 4, 256, 0, stream>>>(zp, Wp2, bp2, out);
}

// Round 7
// 1726.381 us; speedup vs baseline: 1.5746x; 1.0348x over previous
//
#include <hip/hip_runtime.h>

typedef unsigned short u16;
typedef unsigned int u32;
typedef __attribute__((ext_vector_type(8))) short bf16x8_t;
typedef __attribute__((ext_vector_type(4))) float f32x4_t;

// problem constants
#define kN 65536
#define kE 262144
#define kG 2048
#define kH 300
#define kH2 600
#define kL 5
#define kF 32
#define kDG 1523
// padded dims
#define KP_H 320     // K pad of H (mult of 64)
#define KP_H2 640    // K pad of 2H
#define KP_DG 1536   // K pad of DG
#define NP_H2 640    // N pad of 2H (mult of 128)
#define NP_H 384     // N pad of H (mult of 128)
// M-chunking for node MLP
#define C_CHUNK 4
#define C_ROWS (kN / C_CHUNK)   // 16384
// hvbf row stride (u16 / u32)
#define HVS 320
#define HVS32 160

__device__ __forceinline__ float bf2f(u16 x) {
    union { u32 u; float f; } v; v.u = ((u32)x) << 16; return v.f;
}
__device__ __forceinline__ u16 f2bf(float f) {
    union { float f; u32 u; } v; v.f = f;
    u32 u = v.u;
    u32 r = (u + 0x7fffu + ((u >> 16) & 1u)) >> 16;  // RNE
    return (u16)r;
}
__device__ __forceinline__ float blo(u32 v) { return bf2f((u16)(v & 0xffffu)); }
__device__ __forceinline__ float bhi(u32 v) { return bf2f((u16)(v >> 16)); }
__device__ __forceinline__ u32 pack2(float lo, float hi) {
    return (u32)f2bf(lo) | ((u32)f2bf(hi) << 16);
}

// async 16B global -> LDS (wave-uniform lds base; lane writes base + lane*16)
__device__ __forceinline__ void gld16(const u16* g, u16* l) {
    __builtin_amdgcn_global_load_lds(
        (const __attribute__((address_space(1))) u32*)g,
        (__attribute__((address_space(3))) u32*)l, 16, 0, 0);
}

// ---------------- weight transpose: W[b][k][n] (f32) -> Wt[b][n][k] (bf16), zero-padded ----------------
__global__ void transpose_k(const float* __restrict__ W, u16* __restrict__ Wt,
                            int K, int NN, int NP, int KP, long total) {
    long idx = (long)blockIdx.x * 256 + threadIdx.x;
    if (idx >= total) return;
    int per = NP * KP;
    int b = (int)(idx / per);
    int r = (int)(idx % per);
    int n = r / KP;
    int k = r % KP;
    u16 v = 0;
    if (n < NN && k < K) v = f2bf(W[(long)b * K * NN + (long)k * NN + n]);
    Wt[idx] = v;
}

// ---------------- graph histogram + scan (G=2048) ----------------
__global__ void hist_g_k(const int* __restrict__ batch, int* __restrict__ counts) {
    int n = blockIdx.x * 256 + threadIdx.x;
    if (n < kN) atomicAdd(&counts[batch[n]], 1);
}

__global__ void scan_g_k(const int* __restrict__ counts, int* __restrict__ starts) {
    __shared__ int s[1024];
    int t = threadIdx.x;
    int c0 = counts[2 * t], c1 = counts[2 * t + 1];
    s[t] = c0 + c1;
    __syncthreads();
    for (int off = 1; off < 1024; off <<= 1) {
        int v = (t >= off) ? s[t - off] : 0;
        __syncthreads();
        s[t] += v;
        __syncthreads();
    }
    int excl = (t > 0) ? s[t - 1] : 0;
    starts[2 * t] = excl;
    starts[2 * t + 1] = excl + c0;
}

// ---------------- node CSR build (dst-sorted edges), 3-phase scan ----------------
__global__ void hist_n_k(const int* __restrict__ ei, int* __restrict__ cnt) {
    int e = blockIdx.x * 256 + threadIdx.x;
    if (e < kE) atomicAdd(&cnt[ei[kE + e]], 1);  // dst
}

__global__ void scanA_k(const int* __restrict__ cnt, int* __restrict__ start, int* __restrict__ bsum) {
    __shared__ int s[1024];
    int b = blockIdx.x, t = threadIdx.x;
    int v = cnt[b * 1024 + t];
    s[t] = v;
    __syncthreads();
    for (int off = 1; off < 1024; off <<= 1) {
        int u = (t >= off) ? s[t - off] : 0;
        __syncthreads();
        s[t] += u;
        __syncthreads();
    }
    start[b * 1024 + t] = s[t] - v;  // block-local exclusive
    if (t == 1023) bsum[b] = s[1023];
}

__global__ void scanB_k(int* __restrict__ bsum) {
    if (threadIdx.x == 0) {
        int s = 0;
        for (int i = 0; i < kN / 1024; i++) { s += bsum[i]; bsum[i] = s; }  // inclusive
    }
}

__global__ void scanC_k(int* __restrict__ start, const int* __restrict__ bsum) {
    int b = blockIdx.x, t = threadIdx.x;
    int add = (b > 0) ? bsum[b - 1] : 0;
    start[b * 1024 + t] += add;
    if (b == kN / 1024 - 1 && t == 1023) start[kN] = bsum[kN / 1024 - 1];
}

__global__ void fill_n_k(const int* __restrict__ ei, const int* __restrict__ start,
                         int* __restrict__ fill, int* __restrict__ perm) {
    int e = blockIdx.x * 256 + threadIdx.x;
    if (e >= kE) return;
    int s = ei[e], d = ei[kE + e];
    int pos = start[d] + atomicAdd(&fill[d], 1);
    perm[pos] = s;
}

// ---------------- node embedding: hbf = bf16(x @ W_emb + b_emb); hvbf = bf16(. + vn0) ----------------
__global__ void embed_k(const float* __restrict__ x, const float* __restrict__ W,
                        const float* __restrict__ b, u16* __restrict__ hbf,
                        const float* __restrict__ vn0, u16* __restrict__ hvbf) {
    int n = blockIdx.x, j = threadIdx.x;
    if (j >= kH) return;
    float acc = b[j];
    #pragma unroll
    for (int d = 0; d < 9; d++) acc += x[n * 9 + d] * W[d * kH + j];
    hbf[(long)n * kH + j] = f2bf(acc);
    hvbf[(long)n * HVS + j] = f2bf(acc + vn0[j]);
}

__global__ void vninit_k(const float* __restrict__ vn0, float* __restrict__ vn) {
    int g = blockIdx.x, c = threadIdx.x;
    if (c < kH) vn[g * kH + c] = vn0[c];
}

// ---------------- gather + combine: one WAVE per node, u32 (2-col) lanes ----------------
// hv_in[n] = bf16((1+eps)*hvbf[n] + sum_e hvbf[src_e]); zero K-pad; zero stats
__global__ __launch_bounds__(256) void gather_combine_k(
    const u32* __restrict__ hv32, const int* __restrict__ start_n,
    const int* __restrict__ perm, const float* __restrict__ eps, int l,
    u32* __restrict__ out32, float* __restrict__ stats) {
    int tid = threadIdx.x;
    int wave = tid >> 6, lane = tid & 63;
    int n = blockIdx.x * 4 + wave;
    int st = start_n[n], en = start_n[n + 1];
    int i0 = lane, i1 = lane + 64, i2 = lane + 128;
    bool p2 = (i2 < HVS32 - 10);  // i2 < 150 (cols < 300)
    float a0 = 0.f, b0 = 0.f, a1 = 0.f, b1 = 0.f, a2 = 0.f, b2 = 0.f;
    int e = st;
    for (; e + 2 <= en; e += 2) {
        const u32* rA = hv32 + (long)perm[e] * HVS32;
        const u32* rB = hv32 + (long)perm[e + 1] * HVS32;
        u32 vA0 = rA[i0], vA1 = rA[i1], vA2 = p2 ? rA[i2] : 0u;
        u32 vB0 = rB[i0], vB1 = rB[i1], vB2 = p2 ? rB[i2] : 0u;
        a0 += blo(vA0) + blo(vB0); b0 += bhi(vA0) + bhi(vB0);
        a1 += blo(vA1) + blo(vB1); b1 += bhi(vA1) + bhi(vB1);
        a2 += blo(vA2) + blo(vB2); b2 += bhi(vA2) + bhi(vB2);
    }
    if (e < en) {
        const u32* rA = hv32 + (long)perm[e] * HVS32;
        u32 vA0 = rA[i0], vA1 = rA[i1], vA2 = p2 ? rA[i2] : 0u;
        a0 += blo(vA0); b0 += bhi(vA0);
        a1 += blo(vA1); b1 += bhi(vA1);
        a2 += blo(vA2); b2 += bhi(vA2);
    }
    const u32* self = hv32 + (long)n * HVS32;
    float ep = 1.f + eps[l];
    u32 s0 = self[i0], s1 = self[i1];
    u32* o = out32 + (long)n * HVS32;
    o[i0] = pack2(ep * blo(s0) + a0, ep * bhi(s0) + b0);
    o[i1] = pack2(ep * blo(s1) + a1, ep * bhi(s1) + b1);
    if (p2) {
        u32 s2 = self[i2];
        o[i2] = pack2(ep * blo(s2) + a2, ep * bhi(s2) + b2);
    } else if (i2 < HVS32) {
        o[i2] = 0u;  // K-pad cols 300..319
    }
    int gz = blockIdx.x * 256 + tid;
    if (gz < 2 * kH) stats[gz] = 0.f;
}

// ---------------- vt_in[g] = bf16(sum_{rows of g} hvbf + vn[g]) (contiguous rows) ----------------
__global__ void vt_fin_k(const u16* __restrict__ hvbf, const float* __restrict__ vn,
                         const int* __restrict__ counts, const int* __restrict__ starts,
                         u16* __restrict__ vt_in) {
    int g = blockIdx.x, c = threadIdx.x;  // 320
    if (c >= kH) { vt_in[(long)g * KP_H + c] = 0; return; }
    int cnt = counts[g], st = starts[g];
    float acc = vn[g * kH + c];
    for (int i = 0; i < cnt; i++) acc += bf2f(hvbf[(long)(st + i) * HVS + c]);
    vt_in[(long)g * KP_H + c] = f2bf(acc);
}

// ---------------- GEMM: 128x128 tile, BK=64, global_load_lds + XOR-swizzled LDS ----------------
// A: bf16 [M][KP] (zero K-pad). Wt: bf16 [NP][KP] rows (zero-padded). M%128==0, grid.y*128<=NP.
template<int ACT, int OUT_BF16, int BN_STATS>
__global__ __launch_bounds__(256) void gemm_k(
    const u16* __restrict__ A, const u16* __restrict__ Wt,
    const float* __restrict__ bias, void* __restrict__ out,
    float* __restrict__ stats,
    int KP, int NN, int out_stride, int store_cols) {
    __shared__ __align__(16) u16 lA[128 * 64];
    __shared__ __align__(16) u16 lB[128 * 64];
    __shared__ float sred[128][2];

    const int tid = threadIdx.x;
    const int lane = tid & 63;
    const int wave = tid >> 6;
    const int l16 = lane & 15;
    const int quad = lane >> 4;
    const int wm = (wave & 1) * 64;
    const int wn = (wave >> 1) * 64;
    const long tm = (long)blockIdx.x * 128;
    const int tn = blockIdx.y * 128;

    const int srow = lane >> 3;            // 0..7
    const int sch = (lane & 7) ^ srow;     // XOR-swizzled logical k-chunk

    f32x4_t acc[4][4];
    #pragma unroll
    for (int i = 0; i < 4; i++)
        #pragma unroll
        for (int j = 0; j < 4; j++) acc[i][j] = (f32x4_t){0.f, 0.f, 0.f, 0.f};

    for (int k0 = 0; k0 < KP; k0 += 64) {
        __syncthreads();
        #pragma unroll
        for (int j = 0; j < 4; j++) {
            int rb = wave * 32 + j * 8;          // wave-uniform base row
            int r = rb + srow;                   // r & 7 == srow
            gld16(A + (tm + r) * KP + k0 + sch * 8, &lA[rb * 64]);
            gld16(Wt + (long)(tn + r) * KP + k0 + sch * 8, &lB[rb * 64]);
        }
        __syncthreads();
        #pragma unroll
        for (int ks = 0; ks < 2; ks++) {
            bf16x8_t af[4], bfr[4];
            #pragma unroll
            for (int mt = 0; mt < 4; mt++) {
                int row = wm + mt * 16 + l16;
                int phys = (ks * 4 + quad) ^ (l16 & 7);
                af[mt] = *(const bf16x8_t*)&lA[row * 64 + phys * 8];
            }
            #pragma unroll
            for (int nt = 0; nt < 4; nt++) {
                int row = wn + nt * 16 + l16;
                int phys = (ks * 4 + quad) ^ (l16 & 7);
                bfr[nt] = *(const bf16x8_t*)&lB[row * 64 + phys * 8];
            }
            #pragma unroll
            for (int mt = 0; mt < 4; mt++)
                #pragma unroll
                for (int nt = 0; nt < 4; nt++)
                    acc[mt][nt] = __builtin_amdgcn_mfma_f32_16x16x32_bf16(af[mt], bfr[nt], acc[mt][nt], 0, 0, 0);
        }
    }

    if (BN_STATS) {
        if (tid < 128) { sred[tid][0] = 0.f; sred[tid][1] = 0.f; }
    }
    __syncthreads();

    #pragma unroll
    for (int nt = 0; nt < 4; nt++) {
        int col = tn + wn + nt * 16 + l16;
        float bv = (col < NN) ? bias[col] : 0.f;
        float s = 0.f, s2 = 0.f;
        #pragma unroll
        for (int mt = 0; mt < 4; mt++) {
            #pragma unroll
            for (int r = 0; r < 4; r++) {
                long row = tm + wm + mt * 16 + quad * 4 + r;
                float v = acc[mt][nt][r] + bv;
                if (ACT) v = fmaxf(v, 0.f);
                float sv = (col < NN) ? v : 0.f;
                if (col < store_cols) {
                    if (OUT_BF16) ((u16*)out)[row * out_stride + col] = f2bf(sv);
                    else          ((float*)out)[row * out_stride + col] = sv;
                }
                s += sv; s2 += sv * sv;
            }
        }
        if (BN_STATS) {
            atomicAdd(&sred[wn + nt * 16 + l16][0], s);
            atomicAdd(&sred[wn + nt * 16 + l16][1], s2);
        }
    }
    if (BN_STATS) {
        __syncthreads();
        if (tid < 128) {
            int col = tn + tid;
            if (col < NN) {
                atomicAdd(&stats[col], sred[tid][0]);
                atomicAdd(&stats[NN + col], sred[tid][1]);
            }
        }
    }
}

// ---------------- BN-apply + (relu) + residual; h kept in bf16; optionally writes hvbf ----------------
template<int RELU, int WRITE_HV>
__global__ void resid_k(u16* __restrict__ hbf, u16* __restrict__ hvbf,
                        const u16* __restrict__ z, const float* __restrict__ stats,
                        const float* __restrict__ scale, const float* __restrict__ bias, int l,
                        const int* __restrict__ batch, const float* __restrict__ vn) {
    int n = blockIdx.x, c = threadIdx.x;
    if (c >= kH) return;
    float mean = stats[c] * (1.f / (float)kN);
    float var = stats[kH + c] * (1.f / (float)kN) - mean * mean;
    var = fmaxf(var, 0.f);
    float a = scale[l * kH + c] * rsqrtf(var + 1e-5f);
    float b = bias[l * kH + c] - mean * a;
    float v = bf2f(z[(long)n * KP_H + c]) * a + b;
    if (RELU) v = fmaxf(v, 0.f);
    float hn = bf2f(hbf[(long)n * kH + c]) + v;
    hbf[(long)n * kH + c] = f2bf(hn);
    if (WRITE_HV) hvbf[(long)n * HVS + c] = f2bf(hn + vn[batch[n] * kH + c]);
}

__global__ void vnupd_k(float* __restrict__ vn, const float* __restrict__ z) {
    int g = blockIdx.x, c = threadIdx.x;
    if (c < kH) vn[g * kH + c] += fmaxf(z[g * kH + c], 0.f);
}

// ---------------- h_rep cols [0,300): pooled mean of hbf (contiguous rows) ----------------
__global__ void pooled_k(const u16* __restrict__ hbf, const int* __restrict__ counts,
                         const int* __restrict__ starts, u16* __restrict__ hrep) {
    int g = blockIdx.x, c = threadIdx.x;
    if (c >= kH) return;
    int cnt = counts[g], st = starts[g];
    float acc = 0.f;
    for (int i = 0; i < cnt; i++) acc += bf2f(hbf[(long)(st + i) * kH + c]);
    acc /= (float)(cnt > 0 ? cnt : 1);
    hrep[(long)g * KP_DG + c] = f2bf(acc);
}

// ---------------- h_rep cols [300,1536): id_pool | morgan | maccs | zero-pad ----------------
__global__ void hrep_rest_k(const float* __restrict__ morgan, const float* __restrict__ maccs,
                            const int* __restrict__ counts, u16* __restrict__ hrep) {
    long idx = (long)blockIdx.x * 256 + threadIdx.x;
    if (idx >= (long)kG * (KP_DG - kH)) return;
    int g = (int)(idx / (KP_DG - kH));
    int j = (int)(idx % (KP_DG - kH));
    int col = kH + j;
    u16 v;
    if (j < kF) {
        int c = counts[g];
        int q = (j < c) ? ((c - 1 - j) / kF + 1) : 0;  // #k in [0,c) with k%32==j
        v = f2bf((float)q / (float)(c > 0 ? c : 1));
    } else if (j < kF + 1024) {
        v = f2bf(morgan[(long)g * 1024 + (j - kF)]);
    } else if (j < kF + 1024 + 167) {
        v = f2bf(maccs[(long)g * 167 + (j - kF - 1024)]);
    } else {
        v = 0;
    }
    hrep[(long)g * KP_DG + col] = v;
}

// ---------------- final: out[g] = zp[g,:600] . Wp2 + bp2 ----------------
__global__ void final_k(const u16* __restrict__ zp, const float* __restrict__ Wp2,
                        const float* __restrict__ bp2, float* __restrict__ out) {
    int wave = threadIdx.x >> 6, lane = threadIdx.x & 63;
    int g = blockIdx.x * 4 + wave;
    float acc = 0.f;
    for (int c = lane; c < kH2; c += 64) acc += bf2f(zp[(long)g * KP_H2 + c]) * Wp2[c];
    #pragma unroll
    for (int off = 32; off; off >>= 1) acc += __shfl_down(acc, off);
    if (lane == 0) out[g] = acc + bp2[0];
}

extern "C" void kernel_launch(void* const* d_in, const int* in_sizes, int n_in,
                              void* d_out, int out_size, void* d_ws, size_t ws_size,
                              hipStream_t stream) {
    const float* x      = (const float*)d_in[0];
    const float* morgan = (const float*)d_in[1];
    const float* maccs  = (const float*)d_in[2];
    const int*   ei     = (const int*)d_in[3];
    const int*   batch  = (const int*)d_in[4];
    const float* W_emb  = (const float*)d_in[5];
    const float* b_emb  = (const float*)d_in[6];
    const float* gin_W1 = (const float*)d_in[7];
    const float* gin_b1 = (const float*)d_in[8];
    const float* gin_W2 = (const float*)d_in[9];
    const float* gin_b2 = (const float*)d_in[10];
    const float* bn_scale = (const float*)d_in[11];
    const float* bn_bias  = (const float*)d_in[12];
    const float* eps    = (const float*)d_in[13];
    const float* vn0    = (const float*)d_in[14];
    const float* vn_W1  = (const float*)d_in[15];
    const float* vn_b1  = (const float*)d_in[16];
    const float* vn_W2  = (const float*)d_in[17];
    const float* vn_b2  = (const float*)d_in[18];
    const float* Wp1    = (const float*)d_in[19];
    const float* bp1    = (const float*)d_in[20];
    const float* Wp2    = (const float*)d_in[21];
    const float* bp2    = (const float*)d_in[22];
    float* out = (float*)d_out;

    char* ws = (char*)d_ws;
    size_t off = 0;
    auto alloc = [&](size_t bytes) -> char* {
        char* p = ws + off;
        off += (bytes + 255) & ~(size_t)255;
        return p;
    };
    u16*   hbf  = (u16*)alloc((size_t)kN * kH * 2);         // 39.3 MB bf16 h
    u16*   hvbf = (u16*)alloc((size_t)kN * HVS * 2);        // 41.9 MB bf16(h+vn[batch]), padded
    u16*   hv   = (u16*)alloc((size_t)kN * KP_H * 2);       // 41.9 MB (hv_in, then z2 bf16)
    char*  S    = alloc((size_t)C_ROWS * KP_H2 * 2);        // 21.0 MB scratch region
    float* vn   = (float*)alloc((size_t)kG * kH * 4);       // 2.5 MB
    int* counts = (int*)alloc(kG * 4);
    int* starts = (int*)alloc(kG * 4);
    float* stats = (float*)alloc(2 * kH * 4);
    int* cnt_n  = (int*)alloc((size_t)kN * 4);
    int* start_n = (int*)alloc((size_t)(kN + 1) * 4);
    int* fill_n = (int*)alloc((size_t)kN * 4);
    int* bsum   = (int*)alloc((kN / 1024) * 4);
    int* perm   = (int*)alloc((size_t)kE * 4);
    u16* Wt_g1 = (u16*)alloc((size_t)kL * NP_H2 * KP_H * 2);
    u16* Wt_g2 = (u16*)alloc((size_t)kL * NP_H * KP_H2 * 2);
    u16* Wt_v1 = (u16*)alloc((size_t)(kL - 1) * NP_H2 * KP_H * 2);
    u16* Wt_v2 = (u16*)alloc((size_t)(kL - 1) * NP_H * KP_H2 * 2);
    u16* Wt_p1 = (u16*)alloc((size_t)NP_H2 * KP_DG * 2);
    if (off > ws_size) return;  // ~163 MB required

    // scratch-region overlays (disjoint lifetimes vs z1c chunk buffer):
    u16*   z1c   = (u16*)S;                                        // [16384, 640] bf16 (node chunks)
    u16*   vt_in = (u16*)S;                                        // [2048, 320] bf16
    u16*   z1v   = (u16*)(S + (size_t)kG * KP_H * 2);              // [2048, 640] bf16
    float* z2v   = (float*)(S + (size_t)kG * (KP_H + KP_H2) * 2);  // [2048, 300] f32
    u16*   hrep  = (u16*)S;                                        // [2048, 1536] bf16 (post-layers)
    u16*   zp    = (u16*)(S + (size_t)kG * KP_DG * 2);             // [2048, 640] bf16

    // weight transposes (f32 -> padded bf16)
    {
        long t1 = (long)kL * NP_H2 * KP_H;
        transpose_k<<<dim3((unsigned)((t1 + 255) / 256)), 256, 0, stream>>>(gin_W1, Wt_g1, kH, kH2, NP_H2, KP_H, t1);
        long t2 = (long)kL * NP_H * KP_H2;
        transpose_k<<<dim3((unsigned)((t2 + 255) / 256)), 256, 0, stream>>>(gin_W2, Wt_g2, kH2, kH, NP_H, KP_H2, t2);
        long t3 = (long)(kL - 1) * NP_H2 * KP_H;
        transpose_k<<<dim3((unsigned)((t3 + 255) / 256)), 256, 0, stream>>>(vn_W1, Wt_v1, kH, kH2, NP_H2, KP_H, t3);
        long t4 = (long)(kL - 1) * NP_H * KP_H2;
        transpose_k<<<dim3((unsigned)((t4 + 255) / 256)), 256, 0, stream>>>(vn_W2, Wt_v2, kH2, kH, NP_H, KP_H2, t4);
        long t5 = (long)NP_H2 * KP_DG;
        transpose_k<<<dim3((unsigned)((t5 + 255) / 256)), 256, 0, stream>>>(Wp1, Wt_p1, kDG, kH2, NP_H2, KP_DG, t5);
    }

    // graph ranges + node CSR
    hipMemsetAsync(counts, 0, kG * 4, stream);
    hipMemsetAsync(cnt_n, 0, (size_t)kN * 4, stream);
    hipMemsetAsync(fill_n, 0, (size_t)kN * 4, stream);
    hist_g_k<<<kN / 256, 256, 0, stream>>>(batch, counts);
    scan_g_k<<<1, 1024, 0, stream>>>(counts, starts);
    hist_n_k<<<kE / 256, 256, 0, stream>>>(ei, cnt_n);
    scanA_k<<<kN / 1024, 1024, 0, stream>>>(cnt_n, start_n, bsum);
    scanB_k<<<1, 64, 0, stream>>>(bsum);
    scanC_k<<<kN / 1024, 1024, 0, stream>>>(start_n, bsum);
    fill_n_k<<<kE / 256, 256, 0, stream>>>(ei, start_n, fill_n, perm);

    embed_k<<<kN, 320, 0, stream>>>(x, W_emb, b_emb, hbf, vn0, hvbf);
    vninit_k<<<kG, 320, 0, stream>>>(vn0, vn);

    for (int l = 0; l < kL; l++) {
        gather_combine_k<<<kN / 4, 256, 0, stream>>>(
            (const u32*)hvbf, start_n, perm, eps, l, (u32*)hv, stats);
        if (l < kL - 1) {
            vt_fin_k<<<kG, 320, 0, stream>>>(hvbf, vn, counts, starts, vt_in);
            gemm_k<1, 1, 0><<<dim3(16, NP_H2 / 128), 256, 0, stream>>>(
                vt_in, Wt_v1 + (size_t)l * NP_H2 * KP_H, vn_b1 + l * kH2,
                z1v, nullptr, KP_H, kH2, KP_H2, KP_H2);
            gemm_k<0, 0, 0><<<dim3(16, NP_H / 128), 256, 0, stream>>>(
                z1v, Wt_v2 + (size_t)l * NP_H * KP_H2, vn_b2 + l * kH,
                z2v, nullptr, KP_H2, kH, kH, kH);
            vnupd_k<<<kG, 320, 0, stream>>>(vn, z2v);  // vn becomes vn_{l+1}
        }
        // node MLP in M-chunks; z2 (bf16) overwrites hv rows in place
        for (int c = 0; c < C_CHUNK; c++) {
            const u16* Ain = hv + (size_t)c * C_ROWS * KP_H;
            gemm_k<1, 1, 0><<<dim3(C_ROWS / 128, NP_H2 / 128), 256, 0, stream>>>(
                Ain, Wt_g1 + (size_t)l * NP_H2 * KP_H, gin_b1 + l * kH2,
                z1c, nullptr, KP_H, kH2, KP_H2, KP_H2);
            gemm_k<0, 1, 1><<<dim3(C_ROWS / 128, NP_H / 128), 256, 0, stream>>>(
                z1c, Wt_g2 + (size_t)l * NP_H * KP_H2, gin_b2 + l * kH,
                (void*)(hv + (size_t)c * C_ROWS * KP_H), stats, KP_H2, kH, KP_H, KP_H);
        }
        if (l < kL - 1)
            resid_k<1, 1><<<kN, 320, 0, stream>>>(hbf, hvbf, hv, stats, bn_scale, bn_bias, l, batch, vn);
        else
            resid_k<0, 0><<<kN, 320, 0, stream>>>(hbf, hvbf, hv, stats, bn_scale, bn_bias, l, batch, vn);
    }

    pooled_k<<<kG, 320, 0, stream>>>(hbf, counts, starts, hrep);
    {
        long tr = (long)kG * (KP_DG - kH);
        hrep_rest_k<<<dim3((unsigned)((tr + 255) / 256)), 256, 0, stream>>>(morgan, maccs, counts, hrep);
    }
    gemm_k<1, 1, 0><<<dim3(16, NP_H2 / 128), 256, 0, stream>>>(
        hrep, Wt_p1, bp1, zp, nullptr, KP_DG, kH2, KP_H2, KP_H2);
    final_k<<<kG / 4, 256, 0, stream>>>(zp, Wp2, bp2, out);
}